// Round 13
// baseline (969.598 us; speedup 1.0000x reference)
//
#include <hip/hip_runtime.h>
#include <hip/hip_bf16.h>

typedef __attribute__((ext_vector_type(4))) float f32x4;
typedef __attribute__((ext_vector_type(8))) short bf16x8;
typedef __attribute__((ext_vector_type(4))) short bf16x4;

#define NL 6

static __device__ __forceinline__ unsigned short f2bf(float f) {
    __hip_bfloat16 h = __float2bfloat16(f);
    return *reinterpret_cast<unsigned short*>(&h);
}
static __device__ __forceinline__ float bf2f(unsigned short u) {
    union { unsigned int u32; float f; } c; c.u32 = ((unsigned int)u) << 16; return c.f;
}
static __device__ __forceinline__ float gelu_exact(float v) {
    return 0.5f * v * (1.0f + erff(v * 0.70710678118654752f));
}
static __device__ __forceinline__ void gload_lds16(const void* g, void* l) {
    __builtin_amdgcn_global_load_lds((const __attribute__((address_space(1))) void*)g,
                                     (__attribute__((address_space(3))) void*)l, 16, 0, 0);
}
static __device__ __forceinline__ f32x4 MF(bf16x8 a, bf16x8 b, f32x4 c) {
    return __builtin_amdgcn_mfma_f32_16x16x32_bf16(a, b, c, 0, 0, 0);
}

// ============================ GEMM (BK=64, double-buffered LDS) ============================
template<int BM, int BN, bool OBF, bool BIAS, bool GACT, bool SPART, bool DUAL, bool VTR>
__global__ __launch_bounds__(256)
void gemm3(const unsigned short* __restrict__ A, const unsigned short* __restrict__ B,
           void* __restrict__ C, unsigned short* __restrict__ C2,
           const float* __restrict__ bias,
           int M, int N, int nkt, int skN, int lda, int ldb, int ldc, float alpha,
           int modA, long sA1, long sA2, int modB, long sB1, long sB2,
           int modC, long sC1, long sC2, int biasStride, long pStride)
{
    constexpr int MI = BM / 32, NI = BN / 32;
    constexpr int ACH = BM / 8, NCH = (BM + BN) / 8;
    constexpr int HALF = (BM + BN) * 64;
    __shared__ __attribute__((aligned(16))) unsigned short Ls[2 * HALF];

    const int bz = blockIdx.z;
    const int sk = SPART ? (bz % skN) : 0;
    const int z  = SPART ? (bz / skN) : bz;
    const unsigned short* Ab = A + (long)(z % modA) * sA1 + (long)(z / modA) * sA2;
    const unsigned short* Bb = B + (long)(z % modB) * sB1 + (long)(z / modB) * sB2;
    const long offC = (long)(z % modC) * sC1 + (long)(z / modC) * sC2;

    const int bm0 = blockIdx.x * BM, bn0 = blockIdx.y * BN;
    const int t = threadIdx.x, lane = t & 63, w = t >> 6;
    const int wm = (w >> 1) * (BM / 2), wn = (w & 1) * (BN / 2);
    const int crow8 = lane >> 3, cs8 = lane & 7;
    const int fr = lane & 15, kq = lane >> 4;
    const int kBase = sk * nkt * 64;

    auto stagef = [&](int kt, int sb) {
        const int k0 = kBase + (kt << 6);
        const int base = sb * HALF;
        #pragma unroll
        for (int c0 = 0; c0 < NCH; c0 += 4) {
            int c = c0 + w;
            if (c < NCH) {
                const unsigned short* gp;
                if (c < ACH) {
                    int rit = c * 8 + crow8;
                    int ks = cs8 ^ (rit & 7);
                    gp = Ab + (long)(bm0 + rit) * lda + k0 + ks * 8;
                } else {
                    int rit = (c - ACH) * 8 + crow8;
                    int ks = cs8 ^ (rit & 7);
                    gp = Bb + (long)(bn0 + rit) * ldb + k0 + ks * 8;
                }
                gload_lds16(gp, &Ls[base + c * 512]);
            }
        }
    };

    f32x4 acc[MI][NI];
    #pragma unroll
    for (int a = 0; a < MI; a++)
        #pragma unroll
        for (int b = 0; b < NI; b++) acc[a][b] = (f32x4){0.f, 0.f, 0.f, 0.f};

    stagef(0, 0);
    __syncthreads();

    for (int kt = 0; kt < nkt; ++kt) {
        const int sb = kt & 1;
        const int base = sb * HALF;
        if (kt + 1 < nkt) stagef(kt + 1, sb ^ 1);
        bf16x8 af[2][MI], bfr[2][NI];
        #pragma unroll
        for (int mi = 0; mi < MI; mi++) {
            int R = wm + mi * 16 + fr;
            af[0][mi] = *(const bf16x8*)&Ls[base + R * 64 + ((kq ^ (R & 7)) << 3)];
            af[1][mi] = *(const bf16x8*)&Ls[base + R * 64 + (((4 + kq) ^ (R & 7)) << 3)];
        }
        #pragma unroll
        for (int ni = 0; ni < NI; ni++) {
            int Rb = wn + ni * 16 + fr;
            bfr[0][ni] = *(const bf16x8*)&Ls[base + BM * 64 + Rb * 64 + ((kq ^ (Rb & 7)) << 3)];
            bfr[1][ni] = *(const bf16x8*)&Ls[base + BM * 64 + Rb * 64 + (((4 + kq) ^ (Rb & 7)) << 3)];
        }
        #pragma unroll
        for (int kh = 0; kh < 2; kh++)
            #pragma unroll
            for (int mi = 0; mi < MI; mi++)
                #pragma unroll
                for (int ni = 0; ni < NI; ni++)
                    acc[mi][ni] = MF(af[kh][mi], bfr[kh][ni], acc[mi][ni]);
        __syncthreads();
    }

    const int q4 = (lane >> 4) << 2;
    if (VTR && bn0 >= 1024) {
        #pragma unroll
        for (int mi = 0; mi < MI; mi++)
            #pragma unroll
            for (int ni = 0; ni < NI; ni++)
                #pragma unroll
                for (int j = 0; j < 4; j++) {
                    int lr = wm + mi * 16 + q4 + j;
                    int lc = wn + ni * 16 + fr;
                    Ls[lc * 64 + ((((lr >> 4) ^ (lc & 3)) << 4) | (lr & 15))] = f2bf(acc[mi][ni][j]);
                }
        __syncthreads();
        int dl = t >> 2, c4 = (t & 3) << 4;
        const unsigned short* src = &Ls[dl * 64 + (((t & 3) ^ (dl & 3)) << 4)];
        unsigned short* dst = C2 + ((long)((bm0 >> 9) * 8 + ((bn0 - 1024) >> 6)) * 64 + dl) * 512
                              + (bm0 & 511) + c4;
        *(bf16x8*)dst = *(const bf16x8*)src;
        *((bf16x8*)dst + 1) = *((const bf16x8*)src + 1);
    } else if (SPART) {
        float* P = (float*)C + sk * pStride + offC;
        #pragma unroll
        for (int mi = 0; mi < MI; mi++)
            #pragma unroll
            for (int ni = 0; ni < NI; ni++)
                #pragma unroll
                for (int j = 0; j < 4; j++) {
                    int gr = bm0 + wm + mi * 16 + q4 + j;
                    int gc = bn0 + wn + ni * 16 + fr;
                    if (gc < N) P[(long)gr * ldc + gc] = acc[mi][ni][j] * alpha;
                }
    } else {
        float* Cf = (float*)C + offC;
        unsigned short* Ch = (unsigned short*)C + offC;
        unsigned short* C2h = DUAL ? (C2 + offC) : nullptr;
        const float* bp = BIAS ? (bias + (long)z * biasStride) : nullptr;
        #pragma unroll
        for (int mi = 0; mi < MI; mi++)
            #pragma unroll
            for (int ni = 0; ni < NI; ni++)
                #pragma unroll
                for (int j = 0; j < 4; j++) {
                    int gr = bm0 + wm + mi * 16 + q4 + j;
                    int gc = bn0 + wn + ni * 16 + fr;
                    if (gc < N) {
                        float v = acc[mi][ni][j] * alpha;
                        if (BIAS) v += bp[gc];
                        if (GACT) v = gelu_exact(v);
                        if (OBF) Ch[(long)gr * ldc + gc] = f2bf(v);
                        else     Cf[(long)gr * ldc + gc] = v;
                        if (DUAL) C2h[(long)gr * ldc + gc] = f2bf(v);
                    }
                }
    }
}

// ==================== fused flash attention v5: split-KV + in-kernel merge ====================
// grid (8 i-tiles, 32 bh, 2 halves). Second-finishing half merges (device-scope
// atomics + fences per cross-XCD rules). sync[] must be 0 on entry; left 0 on exit.
__global__ __launch_bounds__(256)
void fused_attn5(const unsigned short* __restrict__ qkv,
                 const unsigned short* __restrict__ vt,
                 const unsigned short* __restrict__ rk,
                 const unsigned short* __restrict__ rvt,
                 float* __restrict__ op, float* __restrict__ ml,
                 unsigned int* __restrict__ sync, unsigned short* __restrict__ ctx)
{
    // shorts: Q 0..4096 | K 4096 | V 8192 | RV 12288 | RK 20480 | P 28672 | GA 32768..40960
    __shared__ __attribute__((aligned(16))) unsigned short L[40960];
    __shared__ unsigned int oldS;
    const int bh = blockIdx.y, b = bh >> 3, h = bh & 7;
    const int i0 = blockIdx.x * 64;
    const int half = blockIdx.z;
    const int t = threadIdx.x, lane = t & 63, wv = t >> 6;
    const int crow = lane >> 2, cs = lane & 3;
    const int fr = lane & 15, kq = lane >> 4;
    const int q4 = kq << 2;
    const int iiw = wv * 16;
    const int PB = 28672, GA = 32768;

    const unsigned short* Qg = qkv + ((long)(b * 512 + i0)) * 1536 + h * 64;
    const unsigned short* Kg = qkv + ((long)(b * 512)) * 1536 + 512 + h * 64;
    const unsigned short* Vg = vt + ((long)bh * 64) * 512;

    auto stage = [&](int jt) {
        const int j0 = jt * 64, rbase = j0 - i0 + 448;
        #pragma unroll
        for (int k = 0; k < 12; k++) {
            int c = wv + k * 4;
            const unsigned short* gp; int dst;
            if (c < 8) {
                int kt = c >> 2, row = (c & 3) * 16 + crow, ks = cs ^ (row & 3);
                gp = Kg + (long)(j0 + row) * 1536 + kt * 32 + ks * 8;
                dst = 4096 + c * 512;
            } else if (c < 16) {
                int cc = c - 8;
                int kt = cc >> 2, row = (cc & 3) * 16 + crow, ks = cs ^ (row & 3);
                gp = Vg + (long)row * 512 + j0 + kt * 32 + ks * 8;
                dst = 8192 + cc * 512;
            } else if (c < 32) {
                int cc = c - 16;
                int kt = cc >> 2, row = (cc & 3) * 16 + crow, ks = cs ^ (row & 3);
                gp = rvt + (long)row * 1056 + rbase + kt * 32 + ks * 8;
                dst = 12288 + cc * 512;
            } else {
                int cc = c - 32;
                int kt = cc >> 3, row = (cc & 7) * 16 + crow, ks = cs ^ (row & 3);
                gp = rk + (long)(rbase + row) * 64 + kt * 32 + ks * 8;
                dst = 20480 + cc * 512;
            }
            gload_lds16(gp, &L[dst]);
        }
    };

    #pragma unroll
    for (int k = 0; k < 2; k++) {
        int c = wv + k * 4;
        int kt = c >> 2, row = (c & 3) * 16 + crow, ks = cs ^ (row & 3);
        gload_lds16(Qg + (long)row * 1536 + kt * 32 + ks * 8, &L[c * 512]);
    }
    stage(half * 4);
    __syncthreads();
    bf16x8 qf[2];
    {
        int r = iiw + fr;
        qf[0] = *(const bf16x8*)&L[r * 32 + ((kq ^ (r & 3)) << 3)];
        qf[1] = *(const bf16x8*)&L[2048 + r * 32 + ((kq ^ (r & 3)) << 3)];
    }

    f32x4 ctxa[4];
    #pragma unroll
    for (int ni = 0; ni < 4; ni++) ctxa[ni] = (f32x4){0.f, 0.f, 0.f, 0.f};
    float m_[4] = {-1e30f, -1e30f, -1e30f, -1e30f};
    float l_[4] = {0.f, 0.f, 0.f, 0.f};

    for (int q = 0; q < 4; ++q) {
        const int jt = half * 4 + q;
        // ---- G = Q @ RK_band^T ----
        f32x4 gacc[8];
        #pragma unroll
        for (int wb = 0; wb < 8; wb++) {
            int Rb = wb * 16 + fr;
            bf16x8 rk0 = *(const bf16x8*)&L[20480 + Rb * 32 + ((kq ^ (Rb & 3)) << 3)];
            bf16x8 rk1 = *(const bf16x8*)&L[24576 + Rb * 32 + ((kq ^ (Rb & 3)) << 3)];
            f32x4 g = (f32x4){0.f, 0.f, 0.f, 0.f};
            g = MF(qf[0], rk0, g);
            gacc[wb] = MF(qf[1], rk1, g);
        }
        #pragma unroll
        for (int wb = 0; wb < 8; wb++)
            #pragma unroll
            for (int j = 0; j < 4; j++) {
                int il = iiw + q4 + j, ww = wb * 16 + fr;
                L[GA + il * 128 + (((ww >> 3) ^ (il & 7)) << 3) + (ww & 7)] = f2bf(gacc[wb][j]);
            }
        // ---- S = Q @ K^T ----
        f32x4 s[4];
        #pragma unroll
        for (int ni = 0; ni < 4; ni++) {
            int rB = ni * 16 + fr;
            bf16x8 b0 = *(const bf16x8*)&L[4096 + rB * 32 + ((kq ^ (rB & 3)) << 3)];
            bf16x8 b1 = *(const bf16x8*)&L[6144 + rB * 32 + ((kq ^ (rB & 3)) << 3)];
            f32x4 a0 = (f32x4){0.f, 0.f, 0.f, 0.f};
            a0 = MF(qf[0], b0, a0);
            s[ni] = MF(qf[1], b1, a0);
        }
        #pragma unroll
        for (int ni = 0; ni < 4; ni++)
            #pragma unroll
            for (int j = 0; j < 4; j++) {
                int il = iiw + q4 + j;
                int ww = ni * 16 + fr - il + 64;
                s[ni][j] = s[ni][j] * 0.125f
                         + bf2f(L[GA + il * 128 + (((ww >> 3) ^ (il & 7)) << 3) + (ww & 7)]);
            }
        // ---- online softmax ----
        float mx[4];
        #pragma unroll
        for (int j = 0; j < 4; j++) {
            mx[j] = fmaxf(fmaxf(s[0][j], s[1][j]), fmaxf(s[2][j], s[3][j]));
            #pragma unroll
            for (int msk = 1; msk < 16; msk <<= 1) mx[j] = fmaxf(mx[j], __shfl_xor(mx[j], msk));
        }
        float scl[4];
        #pragma unroll
        for (int j = 0; j < 4; j++) {
            float mn = fmaxf(m_[j], mx[j]);
            scl[j] = __expf(m_[j] - mn);
            m_[j] = mn;
        }
        float rs[4] = {0.f, 0.f, 0.f, 0.f};
        #pragma unroll
        for (int ni = 0; ni < 4; ni++)
            #pragma unroll
            for (int j = 0; j < 4; j++) {
                float p = __expf(s[ni][j] - m_[j]);
                s[ni][j] = p;
                rs[j] += p;
            }
        #pragma unroll
        for (int j = 0; j < 4; j++) {
            #pragma unroll
            for (int msk = 1; msk < 16; msk <<= 1) rs[j] += __shfl_xor(rs[j], msk);
            l_[j] = l_[j] * scl[j] + rs[j];
        }
        #pragma unroll
        for (int ni = 0; ni < 4; ni++)
            #pragma unroll
            for (int j = 0; j < 4; j++) ctxa[ni][j] *= scl[j];
        // ---- write P and shifted A band ----
        #pragma unroll
        for (int ni = 0; ni < 4; ni++)
            #pragma unroll
            for (int j = 0; j < 4; j++) {
                int il = iiw + q4 + j;
                int jj = ni * 16 + fr;
                unsigned short pb = f2bf(s[ni][j]);
                L[PB + il * 64 + (((jj >> 3) ^ (il & 7)) << 3) + (jj & 7)] = pb;
                int wI = jj - il + 64;
                L[GA + il * 128 + (((wI >> 3) ^ (il & 7)) << 3) + (wI & 7)] = pb;
                int wz = (wI + 64) & 127;
                L[GA + il * 128 + (((wz >> 3) ^ (il & 7)) << 3) + (wz & 7)] = 0;
            }
        // ---- PV + A @ relv^T ----
        const int r = iiw + fr;
        bf16x8 pa0 = *(const bf16x8*)&L[PB + r * 64 + ((kq ^ (r & 7)) << 3)];
        bf16x8 pa1 = *(const bf16x8*)&L[PB + r * 64 + (((4 + kq) ^ (r & 7)) << 3)];
        #pragma unroll
        for (int ni = 0; ni < 4; ni++) {
            int rB = ni * 16 + fr;
            bf16x8 vb0 = *(const bf16x8*)&L[8192 + rB * 32 + ((kq ^ (rB & 3)) << 3)];
            bf16x8 vb1 = *(const bf16x8*)&L[10240 + rB * 32 + ((kq ^ (rB & 3)) << 3)];
            ctxa[ni] = MF(pa0, vb0, ctxa[ni]);
            ctxa[ni] = MF(pa1, vb1, ctxa[ni]);
        }
        #pragma unroll
        for (int kt2 = 0; kt2 < 4; kt2++) {
            bf16x8 aa = *(const bf16x8*)&L[GA + r * 128 + (((kt2 * 4 + kq) ^ (r & 7)) << 3)];
            #pragma unroll
            for (int ni = 0; ni < 4; ni++) {
                int rB = ni * 16 + fr;
                bf16x8 rb = *(const bf16x8*)&L[12288 + kt2 * 2048 + rB * 32 + ((kq ^ (rB & 3)) << 3)];
                ctxa[ni] = MF(aa, rb, ctxa[ni]);
            }
        }
        if (q < 3) {
            __syncthreads();
            stage(jt + 1);
            __syncthreads();
        }
    }
    // ---- epilogue: unnormalized ctx + (m,l) ----
    const long prow_base = (long)half * 16384 + (long)bh * 512 + i0;
    #pragma unroll
    for (int j = 0; j < 4; j++) {
        int il = iiw + q4 + j;
        long prow = prow_base + il;
        float* opr = op + prow * 64;
        #pragma unroll
        for (int ni = 0; ni < 4; ni++)
            opr[ni * 16 + fr] = ctxa[ni][j];
        if (fr == 0) {
            ml[prow * 2] = m_[j];
            ml[prow * 2 + 1] = l_[j];
        }
    }
    // ---- second-finisher merges both halves ----
    __syncthreads();
    __threadfence();
    if (t == 0) oldS = atomicAdd(&sync[blockIdx.x * 32 + bh], 1u);
    __syncthreads();
    if (oldS == 1) {
        __threadfence();   // acquire: other half's op/ml visible
        const long r0g = (long)bh * 512 + i0;
        for (int e = t; e < 4096; e += 256) {
            int r = e >> 6, d = e & 63;
            long row = r0g + r;
            float m0 = ml[row * 2], l0 = ml[row * 2 + 1];
            float m1 = ml[(row + 16384) * 2], l1 = ml[(row + 16384) * 2 + 1];
            float m = fmaxf(m0, m1);
            float a0 = __expf(m0 - m), a1 = __expf(m1 - m);
            float inv = 1.f / (l0 * a0 + l1 * a1);
            float o0 = op[row * 64 + d];
            float o1 = op[(row + 16384) * 64 + d];
            ctx[((long)(b * 512 + i0 + r)) * 512 + h * 64 + d] = f2bf((o0 * a0 + o1 * a1) * inv);
        }
        if (t == 0) atomicExch(&sync[blockIdx.x * 32 + bh], 0u);
    }
}

// =================== transpose-cast f32 -> bf16^T (opt scale) ===================
__global__ __launch_bounds__(256)
void trcast_k(const float* __restrict__ in, unsigned short* __restrict__ out,
              int R, int C, int ldo, long inStride, long outStride,
              const float* __restrict__ scp, int sczs)
{
    __shared__ unsigned short tile[32][33];
    const int z = blockIdx.z;
    const float* ip = in + (long)z * inStride;
    unsigned short* op = out + (long)z * outStride;
    const float sc = scp ? scp[z * sczs] : 1.0f;
    const int c0 = blockIdx.x * 32, r0 = blockIdx.y * 32;
    const int tx = threadIdx.x & 31, ty = threadIdx.x >> 5;
    #pragma unroll
    for (int q = 0; q < 4; q++) {
        int r = r0 + ty + q * 8;
        float v = (r < R) ? ip[(long)r * C + c0 + tx] * sc : 0.f;
        tile[ty + q * 8][tx] = f2bf(v);
    }
    __syncthreads();
    #pragma unroll
    for (int q = 0; q < 4; q++) {
        int c = c0 + ty + q * 8;
        op[(long)c * ldo + r0 + tx] = tile[tx][ty + q * 8];
    }
}

// =================== merged [512x512] weight transposes ===================
__global__ __launch_bounds__(256)
void qkvwo_tr(const float* __restrict__ wq, const float* __restrict__ wk,
              const float* __restrict__ wv, const float* __restrict__ wo,
              unsigned short* __restrict__ qkvT, unsigned short* __restrict__ woT)
{
    __shared__ unsigned short tile[32][33];
    const int z = blockIdx.z;
    const int wsel = z / 6, l = z % 6;
    const float* ip = (wsel == 0 ? wq : wsel == 1 ? wk : wsel == 2 ? wv : wo) + (long)l * 262144;
    unsigned short* op = (wsel < 3) ? (qkvT + (long)l * 786432 + (long)wsel * 262144)
                                    : (woT + (long)l * 262144);
    const int c0 = blockIdx.x * 32, r0 = blockIdx.y * 32;
    const int tx = threadIdx.x & 31, ty = threadIdx.x >> 5;
    #pragma unroll
    for (int q = 0; q < 4; q++)
        tile[ty + q * 8][tx] = f2bf(ip[(long)(r0 + ty + q * 8) * 512 + c0 + tx]);
    __syncthreads();
    #pragma unroll
    for (int q = 0; q < 4; q++)
        op[(long)(c0 + ty + q * 8) * 512 + r0 + tx] = tile[tx][ty + q * 8];
}

// =================== seasonal weight prep (merged): z-task-table ===================
// z=0: t1w 512x512 -> W1; z=1: r1w 512x256 -> W1+262144; z=2..4: s1w[k] -> W1+393216+k*131072
// z=5: t2w*c5[0] -> W2 (ld1536); z=6: r2w*c5[4] -> W2+512; z=7..9: s2w[k]*c5[1+k] -> W2+768+k*256
// z=10: bias build (x<8)
__global__ __launch_bounds__(256)
void wprep_k(const float* __restrict__ t1w, const float* __restrict__ r1w,
             const float* __restrict__ s1w, const float* __restrict__ t2w,
             const float* __restrict__ r2w, const float* __restrict__ s2w,
             const float* __restrict__ c5,
             unsigned short* __restrict__ W1, unsigned short* __restrict__ W2,
             const float* __restrict__ t1b, const float* __restrict__ r1b,
             const float* __restrict__ s1b, const float* __restrict__ t2b,
             const float* __restrict__ r2b, const float* __restrict__ s2b,
             float* __restrict__ b1c, float* __restrict__ bc)
{
    const int z = blockIdx.z;
    if (z == 10) {
        int i = threadIdx.x + blockIdx.x * 256;
        if (blockIdx.y != 0 || blockIdx.x >= 8) return;
        if (i < 512) b1c[i] = t1b[i];
        else if (i < 768) b1c[i] = r1b[i - 512];
        else if (i < 1536) b1c[i] = s1b[i - 768];
        else if (i < 2048) {
            int n = i - 1536;
            bc[n] = c5[0] * t2b[n] + c5[4] * r2b[n]
                  + c5[1] * s2b[n] + c5[2] * s2b[512 + n] + c5[3] * s2b[1024 + n];
        }
        return;
    }
    const float* ip; unsigned short* op;
    int R, C, ldo; float sc = 1.0f;
    if (z == 0)      { ip = t1w; op = W1; R = 512; C = 512; ldo = 512; }
    else if (z == 1) { ip = r1w; op = W1 + 262144; R = 512; C = 256; ldo = 512; }
    else if (z <= 4) { int k = z - 2; ip = s1w + (long)k * 131072; op = W1 + 393216 + (long)k * 131072;
                       R = 512; C = 256; ldo = 512; }
    else if (z == 5) { ip = t2w; op = W2; R = 512; C = 512; ldo = 1536; sc = c5[0]; }
    else if (z == 6) { ip = r2w; op = W2 + 512; R = 256; C = 512; ldo = 1536; sc = c5[4]; }
    else             { int k = z - 7; ip = s2w + (long)k * 131072; op = W2 + 768 + (long)k * 256;
                       R = 256; C = 512; ldo = 1536; sc = c5[1 + k]; }
    const int c0 = blockIdx.x * 32, r0 = blockIdx.y * 32;
    if (c0 >= C || r0 >= R) return;
    __shared__ unsigned short tile[32][33];
    const int tx = threadIdx.x & 31, ty = threadIdx.x >> 5;
    #pragma unroll
    for (int q = 0; q < 4; q++) {
        int r = r0 + ty + q * 8;
        float v = (r < R) ? ip[(long)r * C + c0 + tx] * sc : 0.f;
        tile[ty + q * 8][tx] = f2bf(v);
    }
    __syncthreads();
    #pragma unroll
    for (int q = 0; q < 4; q++) {
        int c = c0 + ty + q * 8;
        op[(long)c * ldo + r0 + tx] = tile[tx][ty + q * 8];
    }
}

// =================== cast (+row-pad) f32 -> bf16 ===================
__global__ __launch_bounds__(256)
void castpad_k(const float* __restrict__ in, unsigned short* __restrict__ out,
               int R, int C, long inStride, long outStride, long nPerZ)
{
    const int z = blockIdx.z;
    for (long idx = (long)blockIdx.x * 256 + threadIdx.x; idx < nPerZ;
         idx += (long)gridDim.x * 256) {
        int r = (int)(idx / C);
        float v = (r < R) ? in[(long)z * inStride + idx] : 0.f;
        out[(long)z * outStride + idx] = f2bf(v);
    }
}

// =================== ln2x ===================
__global__ __launch_bounds__(256)
void ln2x_k(const float* __restrict__ p0, const float* __restrict__ p1,
            const float* __restrict__ wb, const float* __restrict__ x,
            const float* __restrict__ g1, const float* __restrict__ b1,
            const float* __restrict__ g2, const float* __restrict__ b2,
            float* __restrict__ yf, unsigned short* __restrict__ yb)
{
    const int wv = threadIdx.x >> 6, lane = threadIdx.x & 63;
    const long row = (long)blockIdx.x * 4 + wv;
    const int base = lane * 8;
    const float* pa = p0 + row * 512 + base;
    const float* pbp = p1 + row * 512 + base;
    const float* px = x + row * 512 + base;
    float xv[8], v[8];
    {
        float4 x0 = *(const float4*)px, x1 = *(const float4*)(px + 4);
        float4 a0 = *(const float4*)pa, a1 = *(const float4*)(pa + 4);
        float4 c0 = *(const float4*)pbp, c1 = *(const float4*)(pbp + 4);
        float4 w0 = *(const float4*)(wb + base), w1 = *(const float4*)(wb + base + 4);
        xv[0] = x0.x; xv[1] = x0.y; xv[2] = x0.z; xv[3] = x0.w;
        xv[4] = x1.x; xv[5] = x1.y; xv[6] = x1.z; xv[7] = x1.w;
        v[0] = xv[0] + a0.x + c0.x + w0.x; v[1] = xv[1] + a0.y + c0.y + w0.y;
        v[2] = xv[2] + a0.z + c0.z + w0.z; v[3] = xv[3] + a0.w + c0.w + w0.w;
        v[4] = xv[4] + a1.x + c1.x + w1.x; v[5] = xv[5] + a1.y + c1.y + w1.y;
        v[6] = xv[6] + a1.z + c1.z + w1.z; v[7] = xv[7] + a1.w + c1.w + w1.w;
    }
    float s = 0.f;
    #pragma unroll
    for (int jj = 0; jj < 8; jj++) s += v[jj];
    #pragma unroll
    for (int off = 32; off; off >>= 1) s += __shfl_xor(s, off);
    float mean = s * (1.f / 512.f);
    float vs = 0.f;
    #pragma unroll
    for (int jj = 0; jj < 8; jj++) { float d = v[jj] - mean; vs += d * d; }
    #pragma unroll
    for (int off = 32; off; off >>= 1) vs += __shfl_xor(vs, off);
    float inv = rsqrtf(vs * (1.f / 512.f) + 1e-5f);
    float4 ga = *(const float4*)(g1 + base), gb = *(const float4*)(g1 + base + 4);
    float4 ba = *(const float4*)(b1 + base), bb = *(const float4*)(b1 + base + 4);
    float gg[8] = {ga.x, ga.y, ga.z, ga.w, gb.x, gb.y, gb.z, gb.w};
    float ee[8] = {ba.x, ba.y, ba.z, ba.w, bb.x, bb.y, bb.z, bb.w};
    float tvec[8];
    #pragma unroll
    for (int jj = 0; jj < 8; jj++) tvec[jj] = xv[jj] + (v[jj] - mean) * inv * gg[jj] + ee[jj];
    float s2 = 0.f;
    #pragma unroll
    for (int jj = 0; jj < 8; jj++) s2 += tvec[jj];
    #pragma unroll
    for (int off = 32; off; off >>= 1) s2 += __shfl_xor(s2, off);
    float m2 = s2 * (1.f / 512.f);
    float vs2 = 0.f;
    #pragma unroll
    for (int jj = 0; jj < 8; jj++) { float d = tvec[jj] - m2; vs2 += d * d; }
    #pragma unroll
    for (int off = 32; off; off >>= 1) vs2 += __shfl_xor(vs2, off);
    float inv2 = rsqrtf(vs2 * (1.f / 512.f) + 1e-5f);
    float4 gc = *(const float4*)(g2 + base), gd = *(const float4*)(g2 + base + 4);
    float4 bc = *(const float4*)(b2 + base), bd = *(const float4*)(b2 + base + 4);
    float g2v[8] = {gc.x, gc.y, gc.z, gc.w, gd.x, gd.y, gd.z, gd.w};
    float b2v[8] = {bc.x, bc.y, bc.z, bc.w, bd.x, bd.y, bd.z, bd.w};
    float r[8];
    #pragma unroll
    for (int jj = 0; jj < 8; jj++) r[jj] = (tvec[jj] - m2) * inv2 * g2v[jj] + b2v[jj];
    float* pf = yf + row * 512 + base;
    *(float4*)pf = (float4){r[0], r[1], r[2], r[3]};
    *(float4*)(pf + 4) = (float4){r[4], r[5], r[6], r[7]};
    bf16x8 ov;
    #pragma unroll
    for (int jj = 0; jj < 8; jj++) ov[jj] = (short)f2bf(r[jj]);
    *(bf16x8*)(yb + row * 512 + base) = ov;
}

// =================== lnff ===================
__global__ __launch_bounds__(256)
void lnff_k(const float* __restrict__ y1, const float* __restrict__ parts,
            const float* __restrict__ bias,
            const float* __restrict__ g, const float* __restrict__ be,
            float* __restrict__ o, unsigned short* __restrict__ ob)
{
    const int wv = threadIdx.x >> 6, lane = threadIdx.x & 63;
    const long row = (long)blockIdx.x * 4 + wv;
    const int base = lane * 8;
    const float* pa = y1 + row * 512 + base;
    float v[8];
    {
        float4 x0 = *(const float4*)pa, x1 = *(const float4*)(pa + 4);
        float4 w0 = *(const float4*)(bias + base), w1 = *(const float4*)(bias + base + 4);
        v[0] = x0.x + w0.x; v[1] = x0.y + w0.y; v[2] = x0.z + w0.z; v[3] = x0.w + w0.w;
        v[4] = x1.x + w1.x; v[5] = x1.y + w1.y; v[6] = x1.z + w1.z; v[7] = x1.w + w1.w;
    }
    #pragma unroll
    for (int k = 0; k < 4; k++) {
        const float* pp = parts + (long)k * 1048576 + row * 512 + base;
        float4 a0 = *(const float4*)pp, a1 = *(const float4*)(pp + 4);
        v[0] += a0.x; v[1] += a0.y; v[2] += a0.z; v[3] += a0.w;
        v[4] += a1.x; v[5] += a1.y; v[6] += a1.z; v[7] += a1.w;
    }
    float s = 0.f;
    #pragma unroll
    for (int jj = 0; jj < 8; jj++) s += v[jj];
    #pragma unroll
    for (int off = 32; off; off >>= 1) s += __shfl_xor(s, off);
    float mean = s * (1.f / 512.f);
    float vs = 0.f;
    #pragma unroll
    for (int jj = 0; jj < 8; jj++) { float d = v[jj] - mean; vs += d * d; }
    #pragma unroll
    for (int off = 32; off; off >>= 1) vs += __shfl_xor(vs, off);
    float inv = rsqrtf(vs * (1.f / 512.f) + 1e-5f);
    float4 g0 = *(const float4*)(g + base), g1 = *(const float4*)(g + base + 4);
    float4 e0 = *(const float4*)(be + base), e1 = *(const float4*)(be + base + 4);
    float gg[8] = {g0.x, g0.y, g0.z, g0.w, g1.x, g1.y, g1.z, g1.w};
    float ee[8] = {e0.x, e0.y, e0.z, e0.w, e1.x, e1.y, e1.z, e1.w};
    float r[8];
    #pragma unroll
    for (int jj = 0; jj < 8; jj++) r[jj] = (v[jj] - mean) * inv * gg[jj] + ee[jj];
    float* po = o + row * 512 + base;
    *(float4*)po = (float4){r[0], r[1], r[2], r[3]};
    *(float4*)(po + 4) = (float4){r[4], r[5], r[6], r[7]};
    bf16x8 ov;
    #pragma unroll
    for (int jj = 0; jj < 8; jj++) ov[jj] = (short)f2bf(r[jj]);
    *(bf16x8*)(ob + row * 512 + base) = ov;
}

// =================== seasonal softmax ===================
__global__ void softmax5_k(const float* __restrict__ comb, float* __restrict__ c5)
{
    if (threadIdx.x == 0 && blockIdx.x == 0) {
        float c[5]; float m = -1e30f;
        for (int k = 0; k < 5; k++) { c[k] = comb[k]; m = fmaxf(m, c[k]); }
        float s = 0.f;
        for (int k = 0; k < 5; k++) { c[k] = __expf(c[k] - m); s += c[k]; }
        for (int k = 0; k < 5; k++) c5[k] = c[k] / s;
    }
}

// ============================ host ============================
#define G3(BM,BN,OBF,BIAS,GACT,SPART,DUAL,VTR, A,B,C,C2,bias_, M,N,NKT,SKN, lda,ldb,ldc, alpha, mA,a1,a2, mB,b1,b2, mC,c1,c2, bstr, pstr, Zg) \
    gemm3<BM,BN,OBF,BIAS,GACT,SPART,DUAL,VTR><<<dim3((M)/(BM), ((N)+(BN)-1)/(BN), (Zg)), dim3(256), 0, stream>>>( \
        (A),(B),(C),(C2),(bias_),(M),(N),(NKT),(SKN),(lda),(ldb),(ldc),(alpha), \
        (mA),(long)(a1),(long)(a2),(mB),(long)(b1),(long)(b2),(mC),(long)(c1),(long)(c2),(bstr),(long)(pstr))

extern "C" void kernel_launch(void* const* d_in, const int* in_sizes, int n_in,
                              void* d_out, int out_size, void* d_ws, size_t ws_size,
                              hipStream_t stream)
{
    (void)in_sizes; (void)n_in; (void)out_size; (void)ws_size;
    const float* x    = (const float*)d_in[0];
    const float* t1w  = (const float*)d_in[1];
    const float* t1b  = (const float*)d_in[2];
    const float* t2w  = (const float*)d_in[3];
    const float* t2b  = (const float*)d_in[4];
    const float* s1w  = (const float*)d_in[5];
    const float* s1b  = (const float*)d_in[6];
    const float* s2w  = (const float*)d_in[7];
    const float* s2b  = (const float*)d_in[8];
    const float* r1w  = (const float*)d_in[9];
    const float* r1b  = (const float*)d_in[10];
    const float* r2w  = (const float*)d_in[11];
    const float* r2b  = (const float*)d_in[12];
    const float* comb = (const float*)d_in[13];
    const float* wq   = (const float*)d_in[14];
    const float* wk   = (const float*)d_in[15];
    const float* wvv  = (const float*)d_in[16];
    const float* wow  = (const float*)d_in[17];
    const float* wob  = (const float*)d_in[18];
    const float* relk = (const float*)d_in[19];
    const float* relv = (const float*)d_in[20];
    const float* lag  = (const float*)d_in[21];
    const float* labi = (const float*)d_in[22];
    const float* f1w  = (const float*)d_in[23];
    const float* f1b  = (const float*)d_in[24];
    const float* f2w  = (const float*)d_in[25];
    const float* f2b  = (const float*)d_in[26];
    const float* n1g  = (const float*)d_in[27];
    const float* n1b  = (const float*)d_in[28];
    const float* n2g  = (const float*)d_in[29];
    const float* n2b  = (const float*)d_in[30];

    char* ws = (char*)d_ws;
    #define OFFK(kb) (ws + (size_t)(kb) * 1024)
    float* X    = (float*)OFFK(0);          // 4MB [2048][512]
    float* T3   = (float*)OFFK(8192);       // 4MB
    float* PART = (float*)OFFK(12288);      // 16MB [4][2048][512]
    float* OP   = PART;                     // attn partials alias (8MB)
    float* ML   = PART + 2097152;           // attn (m,l) alias (256KB)
    unsigned short* Xb   = (unsigned short*)OFFK(45056);  // 2MB
    unsigned short* Xb0  = (unsigned short*)OFFK(47104);  // 2MB
    unsigned short* QKVb = (unsigned short*)OFFK(49152);  // 6MB [2048][1536] (aliases Hb)
    unsigned short* VT   = (unsigned short*)OFFK(55296);  // 2MB [32][64][512]
    unsigned short* CTXb = (unsigned short*)OFFK(57344);  // 2MB
    unsigned short* T3b  = (unsigned short*)OFFK(59392);  // 2MB
    unsigned short* FFb  = (unsigned short*)OFFK(61440);  // 8MB [2048][2048]
    unsigned short* W1   = (unsigned short*)OFFK(69632);  // 1.5MB
    unsigned short* W2   = (unsigned short*)OFFK(71168);  // 1.5MB
    float* b1c = (float*)OFFK(72704);
    float* bc  = (float*)OFFK(72712);
    float* c5  = (float*)OFFK(72716);
    unsigned int* SYNC = (unsigned int*)OFFK(72718);      // 1KB (256 counters)
    unsigned short* qkvT = (unsigned short*)OFFK(119808); // 9MB
    unsigned short* woT  = (unsigned short*)OFFK(129024); // 3MB
    unsigned short* f1wT = (unsigned short*)OFFK(132096); // 12MB
    unsigned short* f2wT = (unsigned short*)OFFK(144384); // 12MB
    unsigned short* relkb= (unsigned short*)OFFK(156672); // [6][1088][64]
    unsigned short* rvT  = (unsigned short*)OFFK(157488); // [6][64][1056]
    unsigned short* Hb   = QKVb;

    // ---------------- prep ----------------
    hipMemsetAsync(SYNC, 0, 1024, stream);
    castpad_k<<<dim3(1024, 1, 1), 256, 0, stream>>>(x, Xb0, 2048, 512, 1048576, 1048576, 1048576);
    softmax5_k<<<dim3(1), 64, 0, stream>>>(comb, c5);
    wprep_k<<<dim3(16, 16, 11), 256, 0, stream>>>(t1w, r1w, s1w, t2w, r2w, s2w, c5, W1, W2,
                                                  t1b, r1b, s1b, t2b, r2b, s2b, b1c, bc);
    qkvwo_tr<<<dim3(16, 16, 24), 256, 0, stream>>>(wq, wk, wvv, wow, qkvT, woT);
    trcast_k<<<dim3(64, 16, 6), 256, 0, stream>>>(f1w, f1wT, 512, 2048, 512, 1048576, 1048576, nullptr, 0);
    trcast_k<<<dim3(16, 64, 6), 256, 0, stream>>>(f2w, f2wT, 2048, 512, 2048, 1048576, 1048576, nullptr, 0);
    trcast_k<<<dim3(2, 33, 6), 256, 0, stream>>>(relv, rvT, 1025, 64, 1056, 65600, 67584, nullptr, 0);
    castpad_k<<<dim3(272, 1, 6), 256, 0, stream>>>(relk, relkb, 1025, 64, 65600, 69632, 69632);

    // ---------------- seasonal decomposition ----------------
    G3(64,64,true,true,true,false,false,false,  Xb0, W1, Hb, nullptr, b1c, 2048,1536,8,1, 512,512,1536, 1.f,
       1,0,0, 1,0,0, 1,0,0, 0,0, 1);
    G3(64,64,false,true,false,false,true,false, Hb, W2, X, Xb, bc, 2048,512,24,1, 1536,1536,512, 1.f,
       1,0,0, 1,0,0, 1,0,0, 0,0, 1);

    // ---------------- transformer layers ----------------
    for (int l = 0; l < NL; ++l) {
        const unsigned short* qkvTl = qkvT + (long)l * 786432;
        const unsigned short* woTl  = woT + (long)l * 262144;
        const unsigned short* f1Tl  = f1wT + (long)l * 1048576;
        const unsigned short* f2Tl  = f2wT + (long)l * 1048576;
        const unsigned short* rkl   = relkb + (long)l * 69632;
        const unsigned short* rvl   = rvT + (long)l * 67584;

        // QKV (merged, 64x64, 768 blocks; V tiles written transposed to VT)
        G3(64,64,true,false,false,false,false,true, Xb, qkvTl, QKVb, VT, nullptr, 2048,1536,8,1, 512,512,1536, 1.f,
           1,0,0, 1,0,0, 1,0,0, 0,0, 1);
        // split-KV flash attention with in-kernel merge (512 blocks)
        fused_attn5<<<dim3(8, 32, 2), 256, 0, stream>>>(QKVb, VT, rkl, rvl, OP, ML, SYNC, CTXb);
        // out = ctx @ wo (64x64, split-K 2 -> 512 blocks)
        G3(64,64,false,false,false,true,false,false, CTXb, woTl, PART, nullptr, nullptr, 2048,512,4,2, 512,512,512, 1.f,
           1,0,0, 1,0,0, 1,0,0, 0,1048576, 2);
        // y1 = LN(x + LN(wo_out + wob + x))
        ln2x_k<<<dim3(512), 256, 0, stream>>>(PART, PART + 1048576, wob + l * 512, X,
                                              lag + l * 512, labi + l * 512,
                                              n1g + l * 512, n1b + l * 512, T3, T3b);
        // FF1 (64x64, 1024 blocks)
        G3(64,64,true,true,true,false,false,false, T3b, f1Tl, FFb, nullptr, f1b + l * 2048, 2048,2048,8,1, 512,512,2048, 1.f,
           1,0,0, 1,0,0, 1,0,0, 0,0, 1);
        // FF2 (64x64, split-K 4 -> 1024 blocks)
        G3(64,64,false,false,false,true,false,false, FFb, f2Tl, PART, nullptr, nullptr, 2048,512,8,4, 2048,2048,512, 1.f,
           1,0,0, 1,0,0, 1,0,0, 0,1048576, 4);
        // y = LN(y1 + ff)
        float* outp = (l == NL - 1) ? (float*)d_out : X;
        lnff_k<<<dim3(512), 256, 0, stream>>>(T3, PART, f2b + l * 512,
                                              n2g + l * 512, n2b + l * 512, outp, Xb);
    }
}

// Round 14
// 538.813 us; speedup vs baseline: 1.7995x; 1.7995x over previous
//
#include <hip/hip_runtime.h>
#include <hip/hip_bf16.h>

typedef __attribute__((ext_vector_type(4))) float f32x4;
typedef __attribute__((ext_vector_type(8))) short bf16x8;
typedef __attribute__((ext_vector_type(4))) short bf16x4;

#define NL 6

static __device__ __forceinline__ unsigned short f2bf(float f) {
    __hip_bfloat16 h = __float2bfloat16(f);
    return *reinterpret_cast<unsigned short*>(&h);
}
static __device__ __forceinline__ float bf2f(unsigned short u) {
    union { unsigned int u32; float f; } c; c.u32 = ((unsigned int)u) << 16; return c.f;
}
static __device__ __forceinline__ float gelu_exact(float v) {
    return 0.5f * v * (1.0f + erff(v * 0.70710678118654752f));
}
static __device__ __forceinline__ void gload_lds16(const void* g, void* l) {
    __builtin_amdgcn_global_load_lds((const __attribute__((address_space(1))) void*)g,
                                     (__attribute__((address_space(3))) void*)l, 16, 0, 0);
}
static __device__ __forceinline__ f32x4 MF(bf16x8 a, bf16x8 b, f32x4 c) {
    return __builtin_amdgcn_mfma_f32_16x16x32_bf16(a, b, c, 0, 0, 0);
}

// ============================ GEMM (BK=64, double-buffered LDS) ============================
template<int BM, int BN, bool OBF, bool BIAS, bool GACT, bool SPART, bool DUAL, bool VTR>
__global__ __launch_bounds__(256)
void gemm3(const unsigned short* __restrict__ A, const unsigned short* __restrict__ B,
           void* __restrict__ C, unsigned short* __restrict__ C2,
           const float* __restrict__ bias,
           int M, int N, int nkt, int skN, int lda, int ldb, int ldc, float alpha,
           int modA, long sA1, long sA2, int modB, long sB1, long sB2,
           int modC, long sC1, long sC2, int biasStride, long pStride)
{
    constexpr int MI = BM / 32, NI = BN / 32;
    constexpr int ACH = BM / 8, NCH = (BM + BN) / 8;
    constexpr int HALF = (BM + BN) * 64;
    __shared__ __attribute__((aligned(16))) unsigned short Ls[2 * HALF];

    const int bz = blockIdx.z;
    const int sk = SPART ? (bz % skN) : 0;
    const int z  = SPART ? (bz / skN) : bz;
    const unsigned short* Ab = A + (long)(z % modA) * sA1 + (long)(z / modA) * sA2;
    const unsigned short* Bb = B + (long)(z % modB) * sB1 + (long)(z / modB) * sB2;
    const long offC = (long)(z % modC) * sC1 + (long)(z / modC) * sC2;

    const int bm0 = blockIdx.x * BM, bn0 = blockIdx.y * BN;
    const int t = threadIdx.x, lane = t & 63, w = t >> 6;
    const int wm = (w >> 1) * (BM / 2), wn = (w & 1) * (BN / 2);
    const int crow8 = lane >> 3, cs8 = lane & 7;
    const int fr = lane & 15, kq = lane >> 4;
    const int kBase = sk * nkt * 64;

    auto stagef = [&](int kt, int sb) {
        const int k0 = kBase + (kt << 6);
        const int base = sb * HALF;
        #pragma unroll
        for (int c0 = 0; c0 < NCH; c0 += 4) {
            int c = c0 + w;
            if (c < NCH) {
                const unsigned short* gp;
                if (c < ACH) {
                    int rit = c * 8 + crow8;
                    int ks = cs8 ^ (rit & 7);
                    gp = Ab + (long)(bm0 + rit) * lda + k0 + ks * 8;
                } else {
                    int rit = (c - ACH) * 8 + crow8;
                    int ks = cs8 ^ (rit & 7);
                    gp = Bb + (long)(bn0 + rit) * ldb + k0 + ks * 8;
                }
                gload_lds16(gp, &Ls[base + c * 512]);
            }
        }
    };

    f32x4 acc[MI][NI];
    #pragma unroll
    for (int a = 0; a < MI; a++)
        #pragma unroll
        for (int b = 0; b < NI; b++) acc[a][b] = (f32x4){0.f, 0.f, 0.f, 0.f};

    stagef(0, 0);
    __syncthreads();

    for (int kt = 0; kt < nkt; ++kt) {
        const int sb = kt & 1;
        const int base = sb * HALF;
        if (kt + 1 < nkt) stagef(kt + 1, sb ^ 1);
        bf16x8 af[2][MI], bfr[2][NI];
        #pragma unroll
        for (int mi = 0; mi < MI; mi++) {
            int R = wm + mi * 16 + fr;
            af[0][mi] = *(const bf16x8*)&Ls[base + R * 64 + ((kq ^ (R & 7)) << 3)];
            af[1][mi] = *(const bf16x8*)&Ls[base + R * 64 + (((4 + kq) ^ (R & 7)) << 3)];
        }
        #pragma unroll
        for (int ni = 0; ni < NI; ni++) {
            int Rb = wn + ni * 16 + fr;
            bfr[0][ni] = *(const bf16x8*)&Ls[base + BM * 64 + Rb * 64 + ((kq ^ (Rb & 7)) << 3)];
            bfr[1][ni] = *(const bf16x8*)&Ls[base + BM * 64 + Rb * 64 + (((4 + kq) ^ (Rb & 7)) << 3)];
        }
        #pragma unroll
        for (int kh = 0; kh < 2; kh++)
            #pragma unroll
            for (int mi = 0; mi < MI; mi++)
                #pragma unroll
                for (int ni = 0; ni < NI; ni++)
                    acc[mi][ni] = MF(af[kh][mi], bfr[kh][ni], acc[mi][ni]);
        __syncthreads();
    }

    const int q4 = (lane >> 4) << 2;
    if (VTR && bn0 >= 1024) {
        #pragma unroll
        for (int mi = 0; mi < MI; mi++)
            #pragma unroll
            for (int ni = 0; ni < NI; ni++)
                #pragma unroll
                for (int j = 0; j < 4; j++) {
                    int lr = wm + mi * 16 + q4 + j;
                    int lc = wn + ni * 16 + fr;
                    Ls[lc * 64 + ((((lr >> 4) ^ (lc & 3)) << 4) | (lr & 15))] = f2bf(acc[mi][ni][j]);
                }
        __syncthreads();
        int dl = t >> 2, c4 = (t & 3) << 4;
        const unsigned short* src = &Ls[dl * 64 + (((t & 3) ^ (dl & 3)) << 4)];
        unsigned short* dst = C2 + ((long)((bm0 >> 9) * 8 + ((bn0 - 1024) >> 6)) * 64 + dl) * 512
                              + (bm0 & 511) + c4;
        *(bf16x8*)dst = *(const bf16x8*)src;
        *((bf16x8*)dst + 1) = *((const bf16x8*)src + 1);
    } else if (SPART) {
        float* P = (float*)C + sk * pStride + offC;
        #pragma unroll
        for (int mi = 0; mi < MI; mi++)
            #pragma unroll
            for (int ni = 0; ni < NI; ni++)
                #pragma unroll
                for (int j = 0; j < 4; j++) {
                    int gr = bm0 + wm + mi * 16 + q4 + j;
                    int gc = bn0 + wn + ni * 16 + fr;
                    if (gc < N) P[(long)gr * ldc + gc] = acc[mi][ni][j] * alpha;
                }
    } else {
        float* Cf = (float*)C + offC;
        unsigned short* Ch = (unsigned short*)C + offC;
        unsigned short* C2h = DUAL ? (C2 + offC) : nullptr;
        const float* bp = BIAS ? (bias + (long)z * biasStride) : nullptr;
        #pragma unroll
        for (int mi = 0; mi < MI; mi++)
            #pragma unroll
            for (int ni = 0; ni < NI; ni++)
                #pragma unroll
                for (int j = 0; j < 4; j++) {
                    int gr = bm0 + wm + mi * 16 + q4 + j;
                    int gc = bn0 + wn + ni * 16 + fr;
                    if (gc < N) {
                        float v = acc[mi][ni][j] * alpha;
                        if (BIAS) v += bp[gc];
                        if (GACT) v = gelu_exact(v);
                        if (OBF) Ch[(long)gr * ldc + gc] = f2bf(v);
                        else     Cf[(long)gr * ldc + gc] = v;
                        if (DUAL) C2h[(long)gr * ldc + gc] = f2bf(v);
                    }
                }
    }
}

// ==================== fused flash attention v4: split-KV, 80KB LDS ====================
__global__ __launch_bounds__(256)
void fused_attn4(const unsigned short* __restrict__ qkv,
                 const unsigned short* __restrict__ vt,
                 const unsigned short* __restrict__ rk,
                 const unsigned short* __restrict__ rvt,
                 float* __restrict__ op, float* __restrict__ ml)
{
    // shorts: Q 0..4096 | K 4096 | V 8192 | RV 12288 | RK 20480 | P 28672 | GA 32768..40960
    __shared__ __attribute__((aligned(16))) unsigned short L[40960];
    const int bh = blockIdx.y, b = bh >> 3, h = bh & 7;
    const int i0 = blockIdx.x * 64;
    const int half = blockIdx.z;
    const int t = threadIdx.x, lane = t & 63, wv = t >> 6;
    const int crow = lane >> 2, cs = lane & 3;
    const int fr = lane & 15, kq = lane >> 4;
    const int q4 = kq << 2;
    const int iiw = wv * 16;
    const int PB = 28672, GA = 32768;

    const unsigned short* Qg = qkv + ((long)(b * 512 + i0)) * 1536 + h * 64;
    const unsigned short* Kg = qkv + ((long)(b * 512)) * 1536 + 512 + h * 64;
    const unsigned short* Vg = vt + ((long)bh * 64) * 512;

    auto stage = [&](int jt) {
        const int j0 = jt * 64, rbase = j0 - i0 + 448;
        #pragma unroll
        for (int k = 0; k < 12; k++) {
            int c = wv + k * 4;
            const unsigned short* gp; int dst;
            if (c < 8) {
                int kt = c >> 2, row = (c & 3) * 16 + crow, ks = cs ^ (row & 3);
                gp = Kg + (long)(j0 + row) * 1536 + kt * 32 + ks * 8;
                dst = 4096 + c * 512;
            } else if (c < 16) {
                int cc = c - 8;
                int kt = cc >> 2, row = (cc & 3) * 16 + crow, ks = cs ^ (row & 3);
                gp = Vg + (long)row * 512 + j0 + kt * 32 + ks * 8;
                dst = 8192 + cc * 512;
            } else if (c < 32) {
                int cc = c - 16;
                int kt = cc >> 2, row = (cc & 3) * 16 + crow, ks = cs ^ (row & 3);
                gp = rvt + (long)row * 1056 + rbase + kt * 32 + ks * 8;
                dst = 12288 + cc * 512;
            } else {
                int cc = c - 32;
                int kt = cc >> 3, row = (cc & 7) * 16 + crow, ks = cs ^ (row & 3);
                gp = rk + (long)(rbase + row) * 64 + kt * 32 + ks * 8;
                dst = 20480 + cc * 512;
            }
            gload_lds16(gp, &L[dst]);
        }
    };

    #pragma unroll
    for (int k = 0; k < 2; k++) {
        int c = wv + k * 4;
        int kt = c >> 2, row = (c & 3) * 16 + crow, ks = cs ^ (row & 3);
        gload_lds16(Qg + (long)row * 1536 + kt * 32 + ks * 8, &L[c * 512]);
    }
    stage(half * 4);
    __syncthreads();
    bf16x8 qf[2];
    {
        int r = iiw + fr;
        qf[0] = *(const bf16x8*)&L[r * 32 + ((kq ^ (r & 3)) << 3)];
        qf[1] = *(const bf16x8*)&L[2048 + r * 32 + ((kq ^ (r & 3)) << 3)];
    }

    f32x4 ctxa[4];
    #pragma unroll
    for (int ni = 0; ni < 4; ni++) ctxa[ni] = (f32x4){0.f, 0.f, 0.f, 0.f};
    float m_[4] = {-1e30f, -1e30f, -1e30f, -1e30f};
    float l_[4] = {0.f, 0.f, 0.f, 0.f};

    for (int q = 0; q < 4; ++q) {
        const int jt = half * 4 + q;
        // ---- G = Q @ RK_band^T ----
        f32x4 gacc[8];
        #pragma unroll
        for (int wb = 0; wb < 8; wb++) {
            int Rb = wb * 16 + fr;
            bf16x8 rk0 = *(const bf16x8*)&L[20480 + Rb * 32 + ((kq ^ (Rb & 3)) << 3)];
            bf16x8 rk1 = *(const bf16x8*)&L[24576 + Rb * 32 + ((kq ^ (Rb & 3)) << 3)];
            f32x4 g = (f32x4){0.f, 0.f, 0.f, 0.f};
            g = MF(qf[0], rk0, g);
            gacc[wb] = MF(qf[1], rk1, g);
        }
        #pragma unroll
        for (int wb = 0; wb < 8; wb++)
            #pragma unroll
            for (int j = 0; j < 4; j++) {
                int il = iiw + q4 + j, ww = wb * 16 + fr;
                L[GA + il * 128 + (((ww >> 3) ^ (il & 7)) << 3) + (ww & 7)] = f2bf(gacc[wb][j]);
            }
        // ---- S = Q @ K^T ----
        f32x4 s[4];
        #pragma unroll
        for (int ni = 0; ni < 4; ni++) {
            int rB = ni * 16 + fr;
            bf16x8 b0 = *(const bf16x8*)&L[4096 + rB * 32 + ((kq ^ (rB & 3)) << 3)];
            bf16x8 b1 = *(const bf16x8*)&L[6144 + rB * 32 + ((kq ^ (rB & 3)) << 3)];
            f32x4 a0 = (f32x4){0.f, 0.f, 0.f, 0.f};
            a0 = MF(qf[0], b0, a0);
            s[ni] = MF(qf[1], b1, a0);
        }
        #pragma unroll
        for (int ni = 0; ni < 4; ni++)
            #pragma unroll
            for (int j = 0; j < 4; j++) {
                int il = iiw + q4 + j;
                int ww = ni * 16 + fr - il + 64;
                s[ni][j] = s[ni][j] * 0.125f
                         + bf2f(L[GA + il * 128 + (((ww >> 3) ^ (il & 7)) << 3) + (ww & 7)]);
            }
        // ---- online softmax ----
        float mx[4];
        #pragma unroll
        for (int j = 0; j < 4; j++) {
            mx[j] = fmaxf(fmaxf(s[0][j], s[1][j]), fmaxf(s[2][j], s[3][j]));
            #pragma unroll
            for (int msk = 1; msk < 16; msk <<= 1) mx[j] = fmaxf(mx[j], __shfl_xor(mx[j], msk));
        }
        float scl[4];
        #pragma unroll
        for (int j = 0; j < 4; j++) {
            float mn = fmaxf(m_[j], mx[j]);
            scl[j] = __expf(m_[j] - mn);
            m_[j] = mn;
        }
        float rs[4] = {0.f, 0.f, 0.f, 0.f};
        #pragma unroll
        for (int ni = 0; ni < 4; ni++)
            #pragma unroll
            for (int j = 0; j < 4; j++) {
                float p = __expf(s[ni][j] - m_[j]);
                s[ni][j] = p;
                rs[j] += p;
            }
        #pragma unroll
        for (int j = 0; j < 4; j++) {
            #pragma unroll
            for (int msk = 1; msk < 16; msk <<= 1) rs[j] += __shfl_xor(rs[j], msk);
            l_[j] = l_[j] * scl[j] + rs[j];
        }
        #pragma unroll
        for (int ni = 0; ni < 4; ni++)
            #pragma unroll
            for (int j = 0; j < 4; j++) ctxa[ni][j] *= scl[j];
        // ---- write P and shifted A band ----
        #pragma unroll
        for (int ni = 0; ni < 4; ni++)
            #pragma unroll
            for (int j = 0; j < 4; j++) {
                int il = iiw + q4 + j;
                int jj = ni * 16 + fr;
                unsigned short pb = f2bf(s[ni][j]);
                L[PB + il * 64 + (((jj >> 3) ^ (il & 7)) << 3) + (jj & 7)] = pb;
                int wI = jj - il + 64;
                L[GA + il * 128 + (((wI >> 3) ^ (il & 7)) << 3) + (wI & 7)] = pb;
                int wz = (wI + 64) & 127;
                L[GA + il * 128 + (((wz >> 3) ^ (il & 7)) << 3) + (wz & 7)] = 0;
            }
        // ---- PV + A @ relv^T ----
        const int r = iiw + fr;
        bf16x8 pa0 = *(const bf16x8*)&L[PB + r * 64 + ((kq ^ (r & 7)) << 3)];
        bf16x8 pa1 = *(const bf16x8*)&L[PB + r * 64 + (((4 + kq) ^ (r & 7)) << 3)];
        #pragma unroll
        for (int ni = 0; ni < 4; ni++) {
            int rB = ni * 16 + fr;
            bf16x8 vb0 = *(const bf16x8*)&L[8192 + rB * 32 + ((kq ^ (rB & 3)) << 3)];
            bf16x8 vb1 = *(const bf16x8*)&L[10240 + rB * 32 + ((kq ^ (rB & 3)) << 3)];
            ctxa[ni] = MF(pa0, vb0, ctxa[ni]);
            ctxa[ni] = MF(pa1, vb1, ctxa[ni]);
        }
        #pragma unroll
        for (int kt2 = 0; kt2 < 4; kt2++) {
            bf16x8 aa = *(const bf16x8*)&L[GA + r * 128 + (((kt2 * 4 + kq) ^ (r & 7)) << 3)];
            #pragma unroll
            for (int ni = 0; ni < 4; ni++) {
                int rB = ni * 16 + fr;
                bf16x8 rb = *(const bf16x8*)&L[12288 + kt2 * 2048 + rB * 32 + ((kq ^ (rB & 3)) << 3)];
                ctxa[ni] = MF(aa, rb, ctxa[ni]);
            }
        }
        if (q < 3) {
            __syncthreads();
            stage(jt + 1);
            __syncthreads();
        }
    }
    const long prow_base = (long)half * 16384 + (long)bh * 512 + i0;
    #pragma unroll
    for (int j = 0; j < 4; j++) {
        int il = iiw + q4 + j;
        long prow = prow_base + il;
        float* opr = op + prow * 64;
        #pragma unroll
        for (int ni = 0; ni < 4; ni++)
            opr[ni * 16 + fr] = ctxa[ni][j];
        if (fr == 0) {
            ml[prow * 2] = m_[j];
            ml[prow * 2 + 1] = l_[j];
        }
    }
}

// ==================== merge the two KV halves ====================
__global__ __launch_bounds__(256)
void attn_merge(const float* __restrict__ op, const float* __restrict__ ml,
                unsigned short* __restrict__ ctx)
{
    const int wv = threadIdx.x >> 6, lane = threadIdx.x & 63;
    const long row = (long)blockIdx.x * 4 + wv;
    const int bh = (int)(row >> 9), i = (int)(row & 511);
    const int b = bh >> 3, h = bh & 7;
    float m0 = ml[row * 2], l0 = ml[row * 2 + 1];
    float m1 = ml[(row + 16384) * 2], l1 = ml[(row + 16384) * 2 + 1];
    float m = fmaxf(m0, m1);
    float a0 = __expf(m0 - m), a1 = __expf(m1 - m);
    float inv = 1.f / (l0 * a0 + l1 * a1);
    float o0 = op[row * 64 + lane];
    float o1 = op[(row + 16384) * 64 + lane];
    ctx[((long)(b * 512 + i)) * 512 + h * 64 + lane] = f2bf((o0 * a0 + o1 * a1) * inv);
}

// =================== transpose-cast f32 -> bf16^T ===================
__global__ __launch_bounds__(256)
void trcast_k(const float* __restrict__ in, unsigned short* __restrict__ out,
              int R, int C, int ldo, long inStride, long outStride,
              const float* __restrict__ scp, int sczs)
{
    __shared__ unsigned short tile[32][33];
    const int z = blockIdx.z;
    const float* ip = in + (long)z * inStride;
    unsigned short* op = out + (long)z * outStride;
    const float sc = scp ? scp[z * sczs] : 1.0f;
    const int c0 = blockIdx.x * 32, r0 = blockIdx.y * 32;
    const int tx = threadIdx.x & 31, ty = threadIdx.x >> 5;
    #pragma unroll
    for (int q = 0; q < 4; q++) {
        int r = r0 + ty + q * 8;
        float v = (r < R) ? ip[(long)r * C + c0 + tx] * sc : 0.f;
        tile[ty + q * 8][tx] = f2bf(v);
    }
    __syncthreads();
    #pragma unroll
    for (int q = 0; q < 4; q++) {
        int c = c0 + ty + q * 8;
        op[(long)c * ldo + r0 + tx] = tile[tx][ty + q * 8];
    }
}

// =================== merged [512x512] weight transposes ===================
__global__ __launch_bounds__(256)
void qkvwo_tr(const float* __restrict__ wq, const float* __restrict__ wk,
              const float* __restrict__ wv, const float* __restrict__ wo,
              unsigned short* __restrict__ qkvT, unsigned short* __restrict__ woT)
{
    __shared__ unsigned short tile[32][33];
    const int z = blockIdx.z;
    const int wsel = z / 6, l = z % 6;
    const float* ip = (wsel == 0 ? wq : wsel == 1 ? wk : wsel == 2 ? wv : wo) + (long)l * 262144;
    unsigned short* op = (wsel < 3) ? (qkvT + (long)l * 786432 + (long)wsel * 262144)
                                    : (woT + (long)l * 262144);
    const int c0 = blockIdx.x * 32, r0 = blockIdx.y * 32;
    const int tx = threadIdx.x & 31, ty = threadIdx.x >> 5;
    #pragma unroll
    for (int q = 0; q < 4; q++)
        tile[ty + q * 8][tx] = f2bf(ip[(long)(r0 + ty + q * 8) * 512 + c0 + tx]);
    __syncthreads();
    #pragma unroll
    for (int q = 0; q < 4; q++)
        op[(long)(c0 + ty + q * 8) * 512 + r0 + tx] = tile[tx][ty + q * 8];
}

// =================== seasonal weight prep (merged): z-task-table ===================
__global__ __launch_bounds__(256)
void wprep_k(const float* __restrict__ t1w, const float* __restrict__ r1w,
             const float* __restrict__ s1w, const float* __restrict__ t2w,
             const float* __restrict__ r2w, const float* __restrict__ s2w,
             const float* __restrict__ c5,
             unsigned short* __restrict__ W1, unsigned short* __restrict__ W2,
             const float* __restrict__ t1b, const float* __restrict__ r1b,
             const float* __restrict__ s1b, const float* __restrict__ t2b,
             const float* __restrict__ r2b, const float* __restrict__ s2b,
             float* __restrict__ b1c, float* __restrict__ bc)
{
    const int z = blockIdx.z;
    if (z == 10) {
        int i = threadIdx.x + blockIdx.x * 256;
        if (blockIdx.y != 0 || blockIdx.x >= 8) return;
        if (i < 512) b1c[i] = t1b[i];
        else if (i < 768) b1c[i] = r1b[i - 512];
        else if (i < 1536) b1c[i] = s1b[i - 768];
        else if (i < 2048) {
            int n = i - 1536;
            bc[n] = c5[0] * t2b[n] + c5[4] * r2b[n]
                  + c5[1] * s2b[n] + c5[2] * s2b[512 + n] + c5[3] * s2b[1024 + n];
        }
        return;
    }
    const float* ip; unsigned short* op;
    int R, C, ldo; float sc = 1.0f;
    if (z == 0)      { ip = t1w; op = W1; R = 512; C = 512; ldo = 512; }
    else if (z == 1) { ip = r1w; op = W1 + 262144; R = 512; C = 256; ldo = 512; }
    else if (z <= 4) { int k = z - 2; ip = s1w + (long)k * 131072; op = W1 + 393216 + (long)k * 131072;
                       R = 512; C = 256; ldo = 512; }
    else if (z == 5) { ip = t2w; op = W2; R = 512; C = 512; ldo = 1536; sc = c5[0]; }
    else if (z == 6) { ip = r2w; op = W2 + 512; R = 256; C = 512; ldo = 1536; sc = c5[4]; }
    else             { int k = z - 7; ip = s2w + (long)k * 131072; op = W2 + 768 + (long)k * 256;
                       R = 256; C = 512; ldo = 1536; sc = c5[1 + k]; }
    const int c0 = blockIdx.x * 32, r0 = blockIdx.y * 32;
    if (c0 >= C || r0 >= R) return;
    __shared__ unsigned short tile[32][33];
    const int tx = threadIdx.x & 31, ty = threadIdx.x >> 5;
    #pragma unroll
    for (int q = 0; q < 4; q++) {
        int r = r0 + ty + q * 8;
        float v = (r < R) ? ip[(long)r * C + c0 + tx] * sc : 0.f;
        tile[ty + q * 8][tx] = f2bf(v);
    }
    __syncthreads();
    #pragma unroll
    for (int q = 0; q < 4; q++) {
        int c = c0 + ty + q * 8;
        op[(long)c * ldo + r0 + tx] = tile[tx][ty + q * 8];
    }
}

// =================== cast (+row-pad) f32 -> bf16 ===================
__global__ __launch_bounds__(256)
void castpad_k(const float* __restrict__ in, unsigned short* __restrict__ out,
               int R, int C, long inStride, long outStride, long nPerZ)
{
    const int z = blockIdx.z;
    for (long idx = (long)blockIdx.x * 256 + threadIdx.x; idx < nPerZ;
         idx += (long)gridDim.x * 256) {
        int r = (int)(idx / C);
        float v = (r < R) ? in[(long)z * inStride + idx] : 0.f;
        out[(long)z * outStride + idx] = f2bf(v);
    }
}

// =================== ln2x ===================
__global__ __launch_bounds__(256)
void ln2x_k(const float* __restrict__ p0, const float* __restrict__ p1,
            const float* __restrict__ wb, const float* __restrict__ x,
            const float* __restrict__ g1, const float* __restrict__ b1,
            const float* __restrict__ g2, const float* __restrict__ b2,
            float* __restrict__ yf, unsigned short* __restrict__ yb)
{
    const int wv = threadIdx.x >> 6, lane = threadIdx.x & 63;
    const long row = (long)blockIdx.x * 4 + wv;
    const int base = lane * 8;
    const float* pa = p0 + row * 512 + base;
    const float* pbp = p1 + row * 512 + base;
    const float* px = x + row * 512 + base;
    float xv[8], v[8];
    {
        float4 x0 = *(const float4*)px, x1 = *(const float4*)(px + 4);
        float4 a0 = *(const float4*)pa, a1 = *(const float4*)(pa + 4);
        float4 c0 = *(const float4*)pbp, c1 = *(const float4*)(pbp + 4);
        float4 w0 = *(const float4*)(wb + base), w1 = *(const float4*)(wb + base + 4);
        xv[0] = x0.x; xv[1] = x0.y; xv[2] = x0.z; xv[3] = x0.w;
        xv[4] = x1.x; xv[5] = x1.y; xv[6] = x1.z; xv[7] = x1.w;
        v[0] = xv[0] + a0.x + c0.x + w0.x; v[1] = xv[1] + a0.y + c0.y + w0.y;
        v[2] = xv[2] + a0.z + c0.z + w0.z; v[3] = xv[3] + a0.w + c0.w + w0.w;
        v[4] = xv[4] + a1.x + c1.x + w1.x; v[5] = xv[5] + a1.y + c1.y + w1.y;
        v[6] = xv[6] + a1.z + c1.z + w1.z; v[7] = xv[7] + a1.w + c1.w + w1.w;
    }
    float s = 0.f;
    #pragma unroll
    for (int jj = 0; jj < 8; jj++) s += v[jj];
    #pragma unroll
    for (int off = 32; off; off >>= 1) s += __shfl_xor(s, off);
    float mean = s * (1.f / 512.f);
    float vs = 0.f;
    #pragma unroll
    for (int jj = 0; jj < 8; jj++) { float d = v[jj] - mean; vs += d * d; }
    #pragma unroll
    for (int off = 32; off; off >>= 1) vs += __shfl_xor(vs, off);
    float inv = rsqrtf(vs * (1.f / 512.f) + 1e-5f);
    float4 ga = *(const float4*)(g1 + base), gb = *(const float4*)(g1 + base + 4);
    float4 ba = *(const float4*)(b1 + base), bb = *(const float4*)(b1 + base + 4);
    float gg[8] = {ga.x, ga.y, ga.z, ga.w, gb.x, gb.y, gb.z, gb.w};
    float ee[8] = {ba.x, ba.y, ba.z, ba.w, bb.x, bb.y, bb.z, bb.w};
    float tvec[8];
    #pragma unroll
    for (int jj = 0; jj < 8; jj++) tvec[jj] = xv[jj] + (v[jj] - mean) * inv * gg[jj] + ee[jj];
    float s2 = 0.f;
    #pragma unroll
    for (int jj = 0; jj < 8; jj++) s2 += tvec[jj];
    #pragma unroll
    for (int off = 32; off; off >>= 1) s2 += __shfl_xor(s2, off);
    float m2 = s2 * (1.f / 512.f);
    float vs2 = 0.f;
    #pragma unroll
    for (int jj = 0; jj < 8; jj++) { float d = tvec[jj] - m2; vs2 += d * d; }
    #pragma unroll
    for (int off = 32; off; off >>= 1) vs2 += __shfl_xor(vs2, off);
    float inv2 = rsqrtf(vs2 * (1.f / 512.f) + 1e-5f);
    float4 gc = *(const float4*)(g2 + base), gd = *(const float4*)(g2 + base + 4);
    float4 bc = *(const float4*)(b2 + base), bd = *(const float4*)(b2 + base + 4);
    float g2v[8] = {gc.x, gc.y, gc.z, gc.w, gd.x, gd.y, gd.z, gd.w};
    float b2v[8] = {bc.x, bc.y, bc.z, bc.w, bd.x, bd.y, bd.z, bd.w};
    float r[8];
    #pragma unroll
    for (int jj = 0; jj < 8; jj++) r[jj] = (tvec[jj] - m2) * inv2 * g2v[jj] + b2v[jj];
    float* pf = yf + row * 512 + base;
    *(float4*)pf = (float4){r[0], r[1], r[2], r[3]};
    *(float4*)(pf + 4) = (float4){r[4], r[5], r[6], r[7]};
    bf16x8 ov;
    #pragma unroll
    for (int jj = 0; jj < 8; jj++) ov[jj] = (short)f2bf(r[jj]);
    *(bf16x8*)(yb + row * 512 + base) = ov;
}

// =================== lnff ===================
__global__ __launch_bounds__(256)
void lnff_k(const float* __restrict__ y1, const float* __restrict__ parts,
            const float* __restrict__ bias,
            const float* __restrict__ g, const float* __restrict__ be,
            float* __restrict__ o, unsigned short* __restrict__ ob)
{
    const int wv = threadIdx.x >> 6, lane = threadIdx.x & 63;
    const long row = (long)blockIdx.x * 4 + wv;
    const int base = lane * 8;
    const float* pa = y1 + row * 512 + base;
    float v[8];
    {
        float4 x0 = *(const float4*)pa, x1 = *(const float4*)(pa + 4);
        float4 w0 = *(const float4*)(bias + base), w1 = *(const float4*)(bias + base + 4);
        v[0] = x0.x + w0.x; v[1] = x0.y + w0.y; v[2] = x0.z + w0.z; v[3] = x0.w + w0.w;
        v[4] = x1.x + w1.x; v[5] = x1.y + w1.y; v[6] = x1.z + w1.z; v[7] = x1.w + w1.w;
    }
    #pragma unroll
    for (int k = 0; k < 4; k++) {
        const float* pp = parts + (long)k * 1048576 + row * 512 + base;
        float4 a0 = *(const float4*)pp, a1 = *(const float4*)(pp + 4);
        v[0] += a0.x; v[1] += a0.y; v[2] += a0.z; v[3] += a0.w;
        v[4] += a1.x; v[5] += a1.y; v[6] += a1.z; v[7] += a1.w;
    }
    float s = 0.f;
    #pragma unroll
    for (int jj = 0; jj < 8; jj++) s += v[jj];
    #pragma unroll
    for (int off = 32; off; off >>= 1) s += __shfl_xor(s, off);
    float mean = s * (1.f / 512.f);
    float vs = 0.f;
    #pragma unroll
    for (int jj = 0; jj < 8; jj++) { float d = v[jj] - mean; vs += d * d; }
    #pragma unroll
    for (int off = 32; off; off >>= 1) vs += __shfl_xor(vs, off);
    float inv = rsqrtf(vs * (1.f / 512.f) + 1e-5f);
    float4 g0 = *(const float4*)(g + base), g1 = *(const float4*)(g + base + 4);
    float4 e0 = *(const float4*)(be + base), e1 = *(const float4*)(be + base + 4);
    float gg[8] = {g0.x, g0.y, g0.z, g0.w, g1.x, g1.y, g1.z, g1.w};
    float ee[8] = {e0.x, e0.y, e0.z, e0.w, e1.x, e1.y, e1.z, e1.w};
    float r[8];
    #pragma unroll
    for (int jj = 0; jj < 8; jj++) r[jj] = (v[jj] - mean) * inv * gg[jj] + ee[jj];
    float* po = o + row * 512 + base;
    *(float4*)po = (float4){r[0], r[1], r[2], r[3]};
    *(float4*)(po + 4) = (float4){r[4], r[5], r[6], r[7]};
    bf16x8 ov;
    #pragma unroll
    for (int jj = 0; jj < 8; jj++) ov[jj] = (short)f2bf(r[jj]);
    *(bf16x8*)(ob + row * 512 + base) = ov;
}

// =================== seasonal softmax ===================
__global__ void softmax5_k(const float* __restrict__ comb, float* __restrict__ c5)
{
    if (threadIdx.x == 0 && blockIdx.x == 0) {
        float c[5]; float m = -1e30f;
        for (int k = 0; k < 5; k++) { c[k] = comb[k]; m = fmaxf(m, c[k]); }
        float s = 0.f;
        for (int k = 0; k < 5; k++) { c[k] = __expf(c[k] - m); s += c[k]; }
        for (int k = 0; k < 5; k++) c5[k] = c[k] / s;
    }
}

// ============================ host ============================
#define G3(BM,BN,OBF,BIAS,GACT,SPART,DUAL,VTR, A,B,C,C2,bias_, M,N,NKT,SKN, lda,ldb,ldc, alpha, mA,a1,a2, mB,b1,b2, mC,c1,c2, bstr, pstr, Zg) \
    gemm3<BM,BN,OBF,BIAS,GACT,SPART,DUAL,VTR><<<dim3((M)/(BM), ((N)+(BN)-1)/(BN), (Zg)), dim3(256), 0, stream>>>( \
        (A),(B),(C),(C2),(bias_),(M),(N),(NKT),(SKN),(lda),(ldb),(ldc),(alpha), \
        (mA),(long)(a1),(long)(a2),(mB),(long)(b1),(long)(b2),(mC),(long)(c1),(long)(c2),(bstr),(long)(pstr))

extern "C" void kernel_launch(void* const* d_in, const int* in_sizes, int n_in,
                              void* d_out, int out_size, void* d_ws, size_t ws_size,
                              hipStream_t stream)
{
    (void)in_sizes; (void)n_in; (void)out_size; (void)ws_size;
    const float* x    = (const float*)d_in[0];
    const float* t1w  = (const float*)d_in[1];
    const float* t1b  = (const float*)d_in[2];
    const float* t2w  = (const float*)d_in[3];
    const float* t2b  = (const float*)d_in[4];
    const float* s1w  = (const float*)d_in[5];
    const float* s1b  = (const float*)d_in[6];
    const float* s2w  = (const float*)d_in[7];
    const float* s2b  = (const float*)d_in[8];
    const float* r1w  = (const float*)d_in[9];
    const float* r1b  = (const float*)d_in[10];
    const float* r2w  = (const float*)d_in[11];
    const float* r2b  = (const float*)d_in[12];
    const float* comb = (const float*)d_in[13];
    const float* wq   = (const float*)d_in[14];
    const float* wk   = (const float*)d_in[15];
    const float* wvv  = (const float*)d_in[16];
    const float* wow  = (const float*)d_in[17];
    const float* wob  = (const float*)d_in[18];
    const float* relk = (const float*)d_in[19];
    const float* relv = (const float*)d_in[20];
    const float* lag  = (const float*)d_in[21];
    const float* labi = (const float*)d_in[22];
    const float* f1w  = (const float*)d_in[23];
    const float* f1b  = (const float*)d_in[24];
    const float* f2w  = (const float*)d_in[25];
    const float* f2b  = (const float*)d_in[26];
    const float* n1g  = (const float*)d_in[27];
    const float* n1b  = (const float*)d_in[28];
    const float* n2g  = (const float*)d_in[29];
    const float* n2b  = (const float*)d_in[30];

    char* ws = (char*)d_ws;
    #define OFFK(kb) (ws + (size_t)(kb) * 1024)
    float* X    = (float*)OFFK(0);          // 4MB [2048][512]
    float* T3   = (float*)OFFK(8192);       // 4MB
    float* PART = (float*)OFFK(12288);      // 16MB [4][2048][512]
    float* OP   = PART;                     // attn partials alias (8MB)
    float* ML   = PART + 2097152;           // attn (m,l) alias (256KB)
    unsigned short* Xb   = (unsigned short*)OFFK(45056);  // 2MB
    unsigned short* Xb0  = (unsigned short*)OFFK(47104);  // 2MB
    unsigned short* QKVb = (unsigned short*)OFFK(49152);  // 6MB [2048][1536] (aliases Hb)
    unsigned short* VT   = (unsigned short*)OFFK(55296);  // 2MB [32][64][512]
    unsigned short* CTXb = (unsigned short*)OFFK(57344);  // 2MB
    unsigned short* T3b  = (unsigned short*)OFFK(59392);  // 2MB
    unsigned short* FFb  = (unsigned short*)OFFK(61440);  // 8MB [2048][2048]
    unsigned short* W1   = (unsigned short*)OFFK(69632);  // 1.5MB
    unsigned short* W2   = (unsigned short*)OFFK(71168);  // 1.5MB
    float* b1c = (float*)OFFK(72704);
    float* bc  = (float*)OFFK(72712);
    float* c5  = (float*)OFFK(72716);
    unsigned short* qkvT = (unsigned short*)OFFK(119808); // 9MB
    unsigned short* woT  = (unsigned short*)OFFK(129024); // 3MB
    unsigned short* f1wT = (unsigned short*)OFFK(132096); // 12MB
    unsigned short* f2wT = (unsigned short*)OFFK(144384); // 12MB
    unsigned short* relkb= (unsigned short*)OFFK(156672); // [6][1088][64]
    unsigned short* rvT  = (unsigned short*)OFFK(157488); // [6][64][1056]
    unsigned short* Hb   = QKVb;

    // ---------------- prep ----------------
    castpad_k<<<dim3(1024, 1, 1), 256, 0, stream>>>(x, Xb0, 2048, 512, 1048576, 1048576, 1048576);
    softmax5_k<<<dim3(1), 64, 0, stream>>>(comb, c5);
    wprep_k<<<dim3(16, 16, 11), 256, 0, stream>>>(t1w, r1w, s1w, t2w, r2w, s2w, c5, W1, W2,
                                                  t1b, r1b, s1b, t2b, r2b, s2b, b1c, bc);
    qkvwo_tr<<<dim3(16, 16, 24), 256, 0, stream>>>(wq, wk, wvv, wow, qkvT, woT);
    trcast_k<<<dim3(64, 16, 6), 256, 0, stream>>>(f1w, f1wT, 512, 2048, 512, 1048576, 1048576, nullptr, 0);
    trcast_k<<<dim3(16, 64, 6), 256, 0, stream>>>(f2w, f2wT, 2048, 512, 2048, 1048576, 1048576, nullptr, 0);
    trcast_k<<<dim3(2, 33, 6), 256, 0, stream>>>(relv, rvT, 1025, 64, 1056, 65600, 67584, nullptr, 0);
    castpad_k<<<dim3(272, 1, 6), 256, 0, stream>>>(relk, relkb, 1025, 64, 65600, 69632, 69632);

    // ---------------- seasonal decomposition ----------------
    G3(64,64,true,true,true,false,false,false,  Xb0, W1, Hb, nullptr, b1c, 2048,1536,8,1, 512,512,1536, 1.f,
       1,0,0, 1,0,0, 1,0,0, 0,0, 1);
    G3(64,64,false,true,false,false,true,false, Hb, W2, X, Xb, bc, 2048,512,24,1, 1536,1536,512, 1.f,
       1,0,0, 1,0,0, 1,0,0, 0,0, 1);

    // ---------------- transformer layers ----------------
    for (int l = 0; l < NL; ++l) {
        const unsigned short* qkvTl = qkvT + (long)l * 786432;
        const unsigned short* woTl  = woT + (long)l * 262144;
        const unsigned short* f1Tl  = f1wT + (long)l * 1048576;
        const unsigned short* f2Tl  = f2wT + (long)l * 1048576;
        const unsigned short* rkl   = relkb + (long)l * 69632;
        const unsigned short* rvl   = rvT + (long)l * 67584;

        // QKV (merged, 64x64, 768 blocks; V tiles written transposed to VT)
        G3(64,64,true,false,false,false,false,true, Xb, qkvTl, QKVb, VT, nullptr, 2048,1536,8,1, 512,512,1536, 1.f,
           1,0,0, 1,0,0, 1,0,0, 0,0, 1);
        // split-KV flash attention (512 blocks, 2/CU) + merge
        fused_attn4<<<dim3(8, 32, 2), 256, 0, stream>>>(QKVb, VT, rkl, rvl, OP, ML);
        attn_merge<<<dim3(4096), 256, 0, stream>>>(OP, ML, CTXb);
        // out = ctx @ wo (64x64, split-K 2 -> 512 blocks)
        G3(64,64,false,false,false,true,false,false, CTXb, woTl, PART, nullptr, nullptr, 2048,512,4,2, 512,512,512, 1.f,
           1,0,0, 1,0,0, 1,0,0, 0,1048576, 2);
        // y1 = LN(x + LN(wo_out + wob + x))
        ln2x_k<<<dim3(512), 256, 0, stream>>>(PART, PART + 1048576, wob + l * 512, X,
                                              lag + l * 512, labi + l * 512,
                                              n1g + l * 512, n1b + l * 512, T3, T3b);
        // FF1 (64x64, 1024 blocks)
        G3(64,64,true,true,true,false,false,false, T3b, f1Tl, FFb, nullptr, f1b + l * 2048, 2048,2048,8,1, 512,512,2048, 1.f,
           1,0,0, 1,0,0, 1,0,0, 0,0, 1);
        // FF2 (64x64, split-K 4 -> 1024 blocks)
        G3(64,64,false,false,false,true,false,false, FFb, f2Tl, PART, nullptr, nullptr, 2048,512,8,4, 2048,2048,512, 1.f,
           1,0,0, 1,0,0, 1,0,0, 0,1048576, 4);
        // y = LN(y1 + ff)
        float* outp = (l == NL - 1) ? (float*)d_out : X;
        lnff_k<<<dim3(512), 256, 0, stream>>>(T3, PART, f2b + l * 512,
                                              n2g + l * 512, n2b + l * 512, outp, Xb);
    }
}

// Round 15
// 534.608 us; speedup vs baseline: 1.8137x; 1.0079x over previous
//
#include <hip/hip_runtime.h>
#include <hip/hip_bf16.h>

typedef __attribute__((ext_vector_type(4))) float f32x4;
typedef __attribute__((ext_vector_type(8))) short bf16x8;
typedef __attribute__((ext_vector_type(4))) short bf16x4;

#define NL 6

static __device__ __forceinline__ unsigned short f2bf(float f) {
    __hip_bfloat16 h = __float2bfloat16(f);
    return *reinterpret_cast<unsigned short*>(&h);
}
static __device__ __forceinline__ float bf2f(unsigned short u) {
    union { unsigned int u32; float f; } c; c.u32 = ((unsigned int)u) << 16; return c.f;
}
static __device__ __forceinline__ float gelu_exact(float v) {
    return 0.5f * v * (1.0f + erff(v * 0.70710678118654752f));
}
static __device__ __forceinline__ void gload_lds16(const void* g, void* l) {
    __builtin_amdgcn_global_load_lds((const __attribute__((address_space(1))) void*)g,
                                     (__attribute__((address_space(3))) void*)l, 16, 0, 0);
}
static __device__ __forceinline__ f32x4 MF(bf16x8 a, bf16x8 b, f32x4 c) {
    return __builtin_amdgcn_mfma_f32_16x16x32_bf16(a, b, c, 0, 0, 0);
}

// ============================ GEMM (BK=64, double-buffered LDS) ============================
template<int BM, int BN, bool OBF, bool BIAS, bool GACT, bool SPART, bool DUAL, bool VTR>
__global__ __launch_bounds__(256)
void gemm3(const unsigned short* __restrict__ A, const unsigned short* __restrict__ B,
           void* __restrict__ C, unsigned short* __restrict__ C2,
           const float* __restrict__ bias,
           int M, int N, int nkt, int skN, int lda, int ldb, int ldc, float alpha,
           int modA, long sA1, long sA2, int modB, long sB1, long sB2,
           int modC, long sC1, long sC2, int biasStride, long pStride)
{
    constexpr int MI = BM / 32, NI = BN / 32;
    constexpr int ACH = BM / 8, NCH = (BM + BN) / 8;
    constexpr int HALF = (BM + BN) * 64;
    __shared__ __attribute__((aligned(16))) unsigned short Ls[2 * HALF];

    const int bz = blockIdx.z;
    const int sk = SPART ? (bz % skN) : 0;
    const int z  = SPART ? (bz / skN) : bz;
    const unsigned short* Ab = A + (long)(z % modA) * sA1 + (long)(z / modA) * sA2;
    const unsigned short* Bb = B + (long)(z % modB) * sB1 + (long)(z / modB) * sB2;
    const long offC = (long)(z % modC) * sC1 + (long)(z / modC) * sC2;

    const int bm0 = blockIdx.x * BM, bn0 = blockIdx.y * BN;
    const int t = threadIdx.x, lane = t & 63, w = t >> 6;
    const int wm = (w >> 1) * (BM / 2), wn = (w & 1) * (BN / 2);
    const int crow8 = lane >> 3, cs8 = lane & 7;
    const int fr = lane & 15, kq = lane >> 4;
    const int kBase = sk * nkt * 64;

    auto stagef = [&](int kt, int sb) {
        const int k0 = kBase + (kt << 6);
        const int base = sb * HALF;
        #pragma unroll
        for (int c0 = 0; c0 < NCH; c0 += 4) {
            int c = c0 + w;
            if (c < NCH) {
                const unsigned short* gp;
                if (c < ACH) {
                    int rit = c * 8 + crow8;
                    int ks = cs8 ^ (rit & 7);
                    gp = Ab + (long)(bm0 + rit) * lda + k0 + ks * 8;
                } else {
                    int rit = (c - ACH) * 8 + crow8;
                    int ks = cs8 ^ (rit & 7);
                    gp = Bb + (long)(bn0 + rit) * ldb + k0 + ks * 8;
                }
                gload_lds16(gp, &Ls[base + c * 512]);
            }
        }
    };

    f32x4 acc[MI][NI];
    #pragma unroll
    for (int a = 0; a < MI; a++)
        #pragma unroll
        for (int b = 0; b < NI; b++) acc[a][b] = (f32x4){0.f, 0.f, 0.f, 0.f};

    stagef(0, 0);
    __syncthreads();

    for (int kt = 0; kt < nkt; ++kt) {
        const int sb = kt & 1;
        const int base = sb * HALF;
        if (kt + 1 < nkt) stagef(kt + 1, sb ^ 1);
        bf16x8 af[2][MI], bfr[2][NI];
        #pragma unroll
        for (int mi = 0; mi < MI; mi++) {
            int R = wm + mi * 16 + fr;
            af[0][mi] = *(const bf16x8*)&Ls[base + R * 64 + ((kq ^ (R & 7)) << 3)];
            af[1][mi] = *(const bf16x8*)&Ls[base + R * 64 + (((4 + kq) ^ (R & 7)) << 3)];
        }
        #pragma unroll
        for (int ni = 0; ni < NI; ni++) {
            int Rb = wn + ni * 16 + fr;
            bfr[0][ni] = *(const bf16x8*)&Ls[base + BM * 64 + Rb * 64 + ((kq ^ (Rb & 7)) << 3)];
            bfr[1][ni] = *(const bf16x8*)&Ls[base + BM * 64 + Rb * 64 + (((4 + kq) ^ (Rb & 7)) << 3)];
        }
        #pragma unroll
        for (int kh = 0; kh < 2; kh++)
            #pragma unroll
            for (int mi = 0; mi < MI; mi++)
                #pragma unroll
                for (int ni = 0; ni < NI; ni++)
                    acc[mi][ni] = MF(af[kh][mi], bfr[kh][ni], acc[mi][ni]);
        __syncthreads();
    }

    const int q4 = (lane >> 4) << 2;
    if (VTR && bn0 >= 1024) {
        #pragma unroll
        for (int mi = 0; mi < MI; mi++)
            #pragma unroll
            for (int ni = 0; ni < NI; ni++)
                #pragma unroll
                for (int j = 0; j < 4; j++) {
                    int lr = wm + mi * 16 + q4 + j;
                    int lc = wn + ni * 16 + fr;
                    Ls[lc * 64 + ((((lr >> 4) ^ (lc & 3)) << 4) | (lr & 15))] = f2bf(acc[mi][ni][j]);
                }
        __syncthreads();
        int dl = t >> 2, c4 = (t & 3) << 4;
        const unsigned short* src = &Ls[dl * 64 + (((t & 3) ^ (dl & 3)) << 4)];
        unsigned short* dst = C2 + ((long)((bm0 >> 9) * 8 + ((bn0 - 1024) >> 6)) * 64 + dl) * 512
                              + (bm0 & 511) + c4;
        *(bf16x8*)dst = *(const bf16x8*)src;
        *((bf16x8*)dst + 1) = *((const bf16x8*)src + 1);
    } else if (SPART) {
        float* P = (float*)C + sk * pStride + offC;
        #pragma unroll
        for (int mi = 0; mi < MI; mi++)
            #pragma unroll
            for (int ni = 0; ni < NI; ni++)
                #pragma unroll
                for (int j = 0; j < 4; j++) {
                    int gr = bm0 + wm + mi * 16 + q4 + j;
                    int gc = bn0 + wn + ni * 16 + fr;
                    if (gc < N) P[(long)gr * ldc + gc] = acc[mi][ni][j] * alpha;
                }
    } else {
        float* Cf = (float*)C + offC;
        unsigned short* Ch = (unsigned short*)C + offC;
        unsigned short* C2h = DUAL ? (C2 + offC) : nullptr;
        const float* bp = BIAS ? (bias + (long)z * biasStride) : nullptr;
        #pragma unroll
        for (int mi = 0; mi < MI; mi++)
            #pragma unroll
            for (int ni = 0; ni < NI; ni++)
                #pragma unroll
                for (int j = 0; j < 4; j++) {
                    int gr = bm0 + wm + mi * 16 + q4 + j;
                    int gc = bn0 + wn + ni * 16 + fr;
                    if (gc < N) {
                        float v = acc[mi][ni][j] * alpha;
                        if (BIAS) v += bp[gc];
                        if (GACT) v = gelu_exact(v);
                        if (OBF) Ch[(long)gr * ldc + gc] = f2bf(v);
                        else     Cf[(long)gr * ldc + gc] = v;
                        if (DUAL) C2h[(long)gr * ldc + gc] = f2bf(v);
                    }
                }
    }
}

// ==================== fused flash attention v4: split-KV, 80KB LDS ====================
__global__ __launch_bounds__(256)
void fused_attn4(const unsigned short* __restrict__ qkv,
                 const unsigned short* __restrict__ vt,
                 const unsigned short* __restrict__ rk,
                 const unsigned short* __restrict__ rvt,
                 float* __restrict__ op, float* __restrict__ ml)
{
    // shorts: Q 0..4096 | K 4096 | V 8192 | RV 12288 | RK 20480 | P 28672 | GA 32768..40960
    __shared__ __attribute__((aligned(16))) unsigned short L[40960];
    const int bh = blockIdx.y, b = bh >> 3, h = bh & 7;
    const int i0 = blockIdx.x * 64;
    const int half = blockIdx.z;
    const int t = threadIdx.x, lane = t & 63, wv = t >> 6;
    const int crow = lane >> 2, cs = lane & 3;
    const int fr = lane & 15, kq = lane >> 4;
    const int q4 = kq << 2;
    const int iiw = wv * 16;
    const int PB = 28672, GA = 32768;

    const unsigned short* Qg = qkv + ((long)(b * 512 + i0)) * 1536 + h * 64;
    const unsigned short* Kg = qkv + ((long)(b * 512)) * 1536 + 512 + h * 64;
    const unsigned short* Vg = vt + ((long)bh * 64) * 512;

    auto stage = [&](int jt) {
        const int j0 = jt * 64, rbase = j0 - i0 + 448;
        #pragma unroll
        for (int k = 0; k < 12; k++) {
            int c = wv + k * 4;
            const unsigned short* gp; int dst;
            if (c < 8) {
                int kt = c >> 2, row = (c & 3) * 16 + crow, ks = cs ^ (row & 3);
                gp = Kg + (long)(j0 + row) * 1536 + kt * 32 + ks * 8;
                dst = 4096 + c * 512;
            } else if (c < 16) {
                int cc = c - 8;
                int kt = cc >> 2, row = (cc & 3) * 16 + crow, ks = cs ^ (row & 3);
                gp = Vg + (long)row * 512 + j0 + kt * 32 + ks * 8;
                dst = 8192 + cc * 512;
            } else if (c < 32) {
                int cc = c - 16;
                int kt = cc >> 2, row = (cc & 3) * 16 + crow, ks = cs ^ (row & 3);
                gp = rvt + (long)row * 1056 + rbase + kt * 32 + ks * 8;
                dst = 12288 + cc * 512;
            } else {
                int cc = c - 32;
                int kt = cc >> 3, row = (cc & 7) * 16 + crow, ks = cs ^ (row & 3);
                gp = rk + (long)(rbase + row) * 64 + kt * 32 + ks * 8;
                dst = 20480 + cc * 512;
            }
            gload_lds16(gp, &L[dst]);
        }
    };

    #pragma unroll
    for (int k = 0; k < 2; k++) {
        int c = wv + k * 4;
        int kt = c >> 2, row = (c & 3) * 16 + crow, ks = cs ^ (row & 3);
        gload_lds16(Qg + (long)row * 1536 + kt * 32 + ks * 8, &L[c * 512]);
    }
    stage(half * 4);
    __syncthreads();
    bf16x8 qf[2];
    {
        int r = iiw + fr;
        qf[0] = *(const bf16x8*)&L[r * 32 + ((kq ^ (r & 3)) << 3)];
        qf[1] = *(const bf16x8*)&L[2048 + r * 32 + ((kq ^ (r & 3)) << 3)];
    }

    f32x4 ctxa[4];
    #pragma unroll
    for (int ni = 0; ni < 4; ni++) ctxa[ni] = (f32x4){0.f, 0.f, 0.f, 0.f};
    float m_[4] = {-1e30f, -1e30f, -1e30f, -1e30f};
    float l_[4] = {0.f, 0.f, 0.f, 0.f};

    for (int q = 0; q < 4; ++q) {
        const int jt = half * 4 + q;
        f32x4 gacc[8];
        #pragma unroll
        for (int wb = 0; wb < 8; wb++) {
            int Rb = wb * 16 + fr;
            bf16x8 rk0 = *(const bf16x8*)&L[20480 + Rb * 32 + ((kq ^ (Rb & 3)) << 3)];
            bf16x8 rk1 = *(const bf16x8*)&L[24576 + Rb * 32 + ((kq ^ (Rb & 3)) << 3)];
            f32x4 g = (f32x4){0.f, 0.f, 0.f, 0.f};
            g = MF(qf[0], rk0, g);
            gacc[wb] = MF(qf[1], rk1, g);
        }
        #pragma unroll
        for (int wb = 0; wb < 8; wb++)
            #pragma unroll
            for (int j = 0; j < 4; j++) {
                int il = iiw + q4 + j, ww = wb * 16 + fr;
                L[GA + il * 128 + (((ww >> 3) ^ (il & 7)) << 3) + (ww & 7)] = f2bf(gacc[wb][j]);
            }
        f32x4 s[4];
        #pragma unroll
        for (int ni = 0; ni < 4; ni++) {
            int rB = ni * 16 + fr;
            bf16x8 b0 = *(const bf16x8*)&L[4096 + rB * 32 + ((kq ^ (rB & 3)) << 3)];
            bf16x8 b1 = *(const bf16x8*)&L[6144 + rB * 32 + ((kq ^ (rB & 3)) << 3)];
            f32x4 a0 = (f32x4){0.f, 0.f, 0.f, 0.f};
            a0 = MF(qf[0], b0, a0);
            s[ni] = MF(qf[1], b1, a0);
        }
        #pragma unroll
        for (int ni = 0; ni < 4; ni++)
            #pragma unroll
            for (int j = 0; j < 4; j++) {
                int il = iiw + q4 + j;
                int ww = ni * 16 + fr - il + 64;
                s[ni][j] = s[ni][j] * 0.125f
                         + bf2f(L[GA + il * 128 + (((ww >> 3) ^ (il & 7)) << 3) + (ww & 7)]);
            }
        float mx[4];
        #pragma unroll
        for (int j = 0; j < 4; j++) {
            mx[j] = fmaxf(fmaxf(s[0][j], s[1][j]), fmaxf(s[2][j], s[3][j]));
            #pragma unroll
            for (int msk = 1; msk < 16; msk <<= 1) mx[j] = fmaxf(mx[j], __shfl_xor(mx[j], msk));
        }
        float scl[4];
        #pragma unroll
        for (int j = 0; j < 4; j++) {
            float mn = fmaxf(m_[j], mx[j]);
            scl[j] = __expf(m_[j] - mn);
            m_[j] = mn;
        }
        float rs[4] = {0.f, 0.f, 0.f, 0.f};
        #pragma unroll
        for (int ni = 0; ni < 4; ni++)
            #pragma unroll
            for (int j = 0; j < 4; j++) {
                float p = __expf(s[ni][j] - m_[j]);
                s[ni][j] = p;
                rs[j] += p;
            }
        #pragma unroll
        for (int j = 0; j < 4; j++) {
            #pragma unroll
            for (int msk = 1; msk < 16; msk <<= 1) rs[j] += __shfl_xor(rs[j], msk);
            l_[j] = l_[j] * scl[j] + rs[j];
        }
        #pragma unroll
        for (int ni = 0; ni < 4; ni++)
            #pragma unroll
            for (int j = 0; j < 4; j++) ctxa[ni][j] *= scl[j];
        #pragma unroll
        for (int ni = 0; ni < 4; ni++)
            #pragma unroll
            for (int j = 0; j < 4; j++) {
                int il = iiw + q4 + j;
                int jj = ni * 16 + fr;
                unsigned short pb = f2bf(s[ni][j]);
                L[PB + il * 64 + (((jj >> 3) ^ (il & 7)) << 3) + (jj & 7)] = pb;
                int wI = jj - il + 64;
                L[GA + il * 128 + (((wI >> 3) ^ (il & 7)) << 3) + (wI & 7)] = pb;
                int wz = (wI + 64) & 127;
                L[GA + il * 128 + (((wz >> 3) ^ (il & 7)) << 3) + (wz & 7)] = 0;
            }
        const int r = iiw + fr;
        bf16x8 pa0 = *(const bf16x8*)&L[PB + r * 64 + ((kq ^ (r & 7)) << 3)];
        bf16x8 pa1 = *(const bf16x8*)&L[PB + r * 64 + (((4 + kq) ^ (r & 7)) << 3)];
        #pragma unroll
        for (int ni = 0; ni < 4; ni++) {
            int rB = ni * 16 + fr;
            bf16x8 vb0 = *(const bf16x8*)&L[8192 + rB * 32 + ((kq ^ (rB & 3)) << 3)];
            bf16x8 vb1 = *(const bf16x8*)&L[10240 + rB * 32 + ((kq ^ (rB & 3)) << 3)];
            ctxa[ni] = MF(pa0, vb0, ctxa[ni]);
            ctxa[ni] = MF(pa1, vb1, ctxa[ni]);
        }
        #pragma unroll
        for (int kt2 = 0; kt2 < 4; kt2++) {
            bf16x8 aa = *(const bf16x8*)&L[GA + r * 128 + (((kt2 * 4 + kq) ^ (r & 7)) << 3)];
            #pragma unroll
            for (int ni = 0; ni < 4; ni++) {
                int rB = ni * 16 + fr;
                bf16x8 rb = *(const bf16x8*)&L[12288 + kt2 * 2048 + rB * 32 + ((kq ^ (rB & 3)) << 3)];
                ctxa[ni] = MF(aa, rb, ctxa[ni]);
            }
        }
        if (q < 3) {
            __syncthreads();
            stage(jt + 1);
            __syncthreads();
        }
    }
    const long prow_base = (long)half * 16384 + (long)bh * 512 + i0;
    #pragma unroll
    for (int j = 0; j < 4; j++) {
        int il = iiw + q4 + j;
        long prow = prow_base + il;
        float* opr = op + prow * 64;
        #pragma unroll
        for (int ni = 0; ni < 4; ni++)
            opr[ni * 16 + fr] = ctxa[ni][j];
        if (fr == 0) {
            ml[prow * 2] = m_[j];
            ml[prow * 2 + 1] = l_[j];
        }
    }
}

// ==================== merge the two KV halves ====================
__global__ __launch_bounds__(256)
void attn_merge(const float* __restrict__ op, const float* __restrict__ ml,
                unsigned short* __restrict__ ctx)
{
    const int wv = threadIdx.x >> 6, lane = threadIdx.x & 63;
    const long row = (long)blockIdx.x * 4 + wv;
    const int bh = (int)(row >> 9), i = (int)(row & 511);
    const int b = bh >> 3, h = bh & 7;
    float m0 = ml[row * 2], l0 = ml[row * 2 + 1];
    float m1 = ml[(row + 16384) * 2], l1 = ml[(row + 16384) * 2 + 1];
    float m = fmaxf(m0, m1);
    float a0 = __expf(m0 - m), a1 = __expf(m1 - m);
    float inv = 1.f / (l0 * a0 + l1 * a1);
    float o0 = op[row * 64 + lane];
    float o1 = op[(row + 16384) * 64 + lane];
    ctx[((long)(b * 512 + i)) * 512 + h * 64 + lane] = f2bf((o0 * a0 + o1 * a1) * inv);
}

// =================== red3xb: X = sum3(parts)+bias -> f32 + bf16 ===================
__global__ __launch_bounds__(256)
void red3xb_k(const float* __restrict__ parts, const float* __restrict__ bias,
              float* __restrict__ of, unsigned short* __restrict__ ob)
{
    long i4 = ((long)blockIdx.x * 256 + threadIdx.x) * 4;
    float4 s = *(const float4*)(parts + i4);
    float4 p1 = *(const float4*)(parts + 1048576 + i4);
    float4 p2 = *(const float4*)(parts + 2097152 + i4);
    float4 bv = *(const float4*)(bias + (int)(i4 & 511));
    s.x += p1.x + p2.x + bv.x; s.y += p1.y + p2.y + bv.y;
    s.z += p1.z + p2.z + bv.z; s.w += p1.w + p2.w + bv.w;
    *(float4*)(of + i4) = s;
    bf16x4 o = {(short)f2bf(s.x), (short)f2bf(s.y), (short)f2bf(s.z), (short)f2bf(s.w)};
    *(bf16x4*)(ob + i4) = o;
}

// =================== transpose-cast f32 -> bf16^T ===================
__global__ __launch_bounds__(256)
void trcast_k(const float* __restrict__ in, unsigned short* __restrict__ out,
              int R, int C, int ldo, long inStride, long outStride,
              const float* __restrict__ scp, int sczs)
{
    __shared__ unsigned short tile[32][33];
    const int z = blockIdx.z;
    const float* ip = in + (long)z * inStride;
    unsigned short* op = out + (long)z * outStride;
    const float sc = scp ? scp[z * sczs] : 1.0f;
    const int c0 = blockIdx.x * 32, r0 = blockIdx.y * 32;
    const int tx = threadIdx.x & 31, ty = threadIdx.x >> 5;
    #pragma unroll
    for (int q = 0; q < 4; q++) {
        int r = r0 + ty + q * 8;
        float v = (r < R) ? ip[(long)r * C + c0 + tx] * sc : 0.f;
        tile[ty + q * 8][tx] = f2bf(v);
    }
    __syncthreads();
    #pragma unroll
    for (int q = 0; q < 4; q++) {
        int c = c0 + ty + q * 8;
        op[(long)c * ldo + r0 + tx] = tile[tx][ty + q * 8];
    }
}

// =================== merged [512x512] weight transposes ===================
__global__ __launch_bounds__(256)
void qkvwo_tr(const float* __restrict__ wq, const float* __restrict__ wk,
              const float* __restrict__ wv, const float* __restrict__ wo,
              unsigned short* __restrict__ qkvT, unsigned short* __restrict__ woT)
{
    __shared__ unsigned short tile[32][33];
    const int z = blockIdx.z;
    const int wsel = z / 6, l = z % 6;
    const float* ip = (wsel == 0 ? wq : wsel == 1 ? wk : wsel == 2 ? wv : wo) + (long)l * 262144;
    unsigned short* op = (wsel < 3) ? (qkvT + (long)l * 786432 + (long)wsel * 262144)
                                    : (woT + (long)l * 262144);
    const int c0 = blockIdx.x * 32, r0 = blockIdx.y * 32;
    const int tx = threadIdx.x & 31, ty = threadIdx.x >> 5;
    #pragma unroll
    for (int q = 0; q < 4; q++)
        tile[ty + q * 8][tx] = f2bf(ip[(long)(r0 + ty + q * 8) * 512 + c0 + tx]);
    __syncthreads();
    #pragma unroll
    for (int q = 0; q < 4; q++)
        op[(long)(c0 + ty + q * 8) * 512 + r0 + tx] = tile[tx][ty + q * 8];
}

// =================== seasonal weight prep (merged): z-task-table ===================
__global__ __launch_bounds__(256)
void wprep_k(const float* __restrict__ t1w, const float* __restrict__ r1w,
             const float* __restrict__ s1w, const float* __restrict__ t2w,
             const float* __restrict__ r2w, const float* __restrict__ s2w,
             const float* __restrict__ c5,
             unsigned short* __restrict__ W1, unsigned short* __restrict__ W2,
             const float* __restrict__ t1b, const float* __restrict__ r1b,
             const float* __restrict__ s1b, const float* __restrict__ t2b,
             const float* __restrict__ r2b, const float* __restrict__ s2b,
             float* __restrict__ b1c, float* __restrict__ bc)
{
    const int z = blockIdx.z;
    if (z == 10) {
        int i = threadIdx.x + blockIdx.x * 256;
        if (blockIdx.y != 0 || blockIdx.x >= 8) return;
        if (i < 512) b1c[i] = t1b[i];
        else if (i < 768) b1c[i] = r1b[i - 512];
        else if (i < 1536) b1c[i] = s1b[i - 768];
        else if (i < 2048) {
            int n = i - 1536;
            bc[n] = c5[0] * t2b[n] + c5[4] * r2b[n]
                  + c5[1] * s2b[n] + c5[2] * s2b[512 + n] + c5[3] * s2b[1024 + n];
        }
        return;
    }
    const float* ip; unsigned short* op;
    int R, C, ldo; float sc = 1.0f;
    if (z == 0)      { ip = t1w; op = W1; R = 512; C = 512; ldo = 512; }
    else if (z == 1) { ip = r1w; op = W1 + 262144; R = 512; C = 256; ldo = 512; }
    else if (z <= 4) { int k = z - 2; ip = s1w + (long)k * 131072; op = W1 + 393216 + (long)k * 131072;
                       R = 512; C = 256; ldo = 512; }
    else if (z == 5) { ip = t2w; op = W2; R = 512; C = 512; ldo = 1536; sc = c5[0]; }
    else if (z == 6) { ip = r2w; op = W2 + 512; R = 256; C = 512; ldo = 1536; sc = c5[4]; }
    else             { int k = z - 7; ip = s2w + (long)k * 131072; op = W2 + 768 + (long)k * 256;
                       R = 256; C = 512; ldo = 1536; sc = c5[1 + k]; }
    const int c0 = blockIdx.x * 32, r0 = blockIdx.y * 32;
    if (c0 >= C || r0 >= R) return;
    __shared__ unsigned short tile[32][33];
    const int tx = threadIdx.x & 31, ty = threadIdx.x >> 5;
    #pragma unroll
    for (int q = 0; q < 4; q++) {
        int r = r0 + ty + q * 8;
        float v = (r < R) ? ip[(long)r * C + c0 + tx] * sc : 0.f;
        tile[ty + q * 8][tx] = f2bf(v);
    }
    __syncthreads();
    #pragma unroll
    for (int q = 0; q < 4; q++) {
        int c = c0 + ty + q * 8;
        op[(long)c * ldo + r0 + tx] = tile[tx][ty + q * 8];
    }
}

// =================== cast (+row-pad) f32 -> bf16 ===================
__global__ __launch_bounds__(256)
void castpad_k(const float* __restrict__ in, unsigned short* __restrict__ out,
               int R, int C, long inStride, long outStride, long nPerZ)
{
    const int z = blockIdx.z;
    for (long idx = (long)blockIdx.x * 256 + threadIdx.x; idx < nPerZ;
         idx += (long)gridDim.x * 256) {
        int r = (int)(idx / C);
        float v = (r < R) ? in[(long)z * inStride + idx] : 0.f;
        out[(long)z * outStride + idx] = f2bf(v);
    }
}

// =================== ln2x ===================
__global__ __launch_bounds__(256)
void ln2x_k(const float* __restrict__ p0, const float* __restrict__ p1,
            const float* __restrict__ wb, const float* __restrict__ x,
            const float* __restrict__ g1, const float* __restrict__ b1,
            const float* __restrict__ g2, const float* __restrict__ b2,
            float* __restrict__ yf, unsigned short* __restrict__ yb)
{
    const int wv = threadIdx.x >> 6, lane = threadIdx.x & 63;
    const long row = (long)blockIdx.x * 4 + wv;
    const int base = lane * 8;
    const float* pa = p0 + row * 512 + base;
    const float* pbp = p1 + row * 512 + base;
    const float* px = x + row * 512 + base;
    float xv[8], v[8];
    {
        float4 x0 = *(const float4*)px, x1 = *(const float4*)(px + 4);
        float4 a0 = *(const float4*)pa, a1 = *(const float4*)(pa + 4);
        float4 c0 = *(const float4*)pbp, c1 = *(const float4*)(pbp + 4);
        float4 w0 = *(const float4*)(wb + base), w1 = *(const float4*)(wb + base + 4);
        xv[0] = x0.x; xv[1] = x0.y; xv[2] = x0.z; xv[3] = x0.w;
        xv[4] = x1.x; xv[5] = x1.y; xv[6] = x1.z; xv[7] = x1.w;
        v[0] = xv[0] + a0.x + c0.x + w0.x; v[1] = xv[1] + a0.y + c0.y + w0.y;
        v[2] = xv[2] + a0.z + c0.z + w0.z; v[3] = xv[3] + a0.w + c0.w + w0.w;
        v[4] = xv[4] + a1.x + c1.x + w1.x; v[5] = xv[5] + a1.y + c1.y + w1.y;
        v[6] = xv[6] + a1.z + c1.z + w1.z; v[7] = xv[7] + a1.w + c1.w + w1.w;
    }
    float s = 0.f;
    #pragma unroll
    for (int jj = 0; jj < 8; jj++) s += v[jj];
    #pragma unroll
    for (int off = 32; off; off >>= 1) s += __shfl_xor(s, off);
    float mean = s * (1.f / 512.f);
    float vs = 0.f;
    #pragma unroll
    for (int jj = 0; jj < 8; jj++) { float d = v[jj] - mean; vs += d * d; }
    #pragma unroll
    for (int off = 32; off; off >>= 1) vs += __shfl_xor(vs, off);
    float inv = rsqrtf(vs * (1.f / 512.f) + 1e-5f);
    float4 ga = *(const float4*)(g1 + base), gb = *(const float4*)(g1 + base + 4);
    float4 ba = *(const float4*)(b1 + base), bb = *(const float4*)(b1 + base + 4);
    float gg[8] = {ga.x, ga.y, ga.z, ga.w, gb.x, gb.y, gb.z, gb.w};
    float ee[8] = {ba.x, ba.y, ba.z, ba.w, bb.x, bb.y, bb.z, bb.w};
    float tvec[8];
    #pragma unroll
    for (int jj = 0; jj < 8; jj++) tvec[jj] = xv[jj] + (v[jj] - mean) * inv * gg[jj] + ee[jj];
    float s2 = 0.f;
    #pragma unroll
    for (int jj = 0; jj < 8; jj++) s2 += tvec[jj];
    #pragma unroll
    for (int off = 32; off; off >>= 1) s2 += __shfl_xor(s2, off);
    float m2 = s2 * (1.f / 512.f);
    float vs2 = 0.f;
    #pragma unroll
    for (int jj = 0; jj < 8; jj++) { float d = tvec[jj] - m2; vs2 += d * d; }
    #pragma unroll
    for (int off = 32; off; off >>= 1) vs2 += __shfl_xor(vs2, off);
    float inv2 = rsqrtf(vs2 * (1.f / 512.f) + 1e-5f);
    float4 gc = *(const float4*)(g2 + base), gd = *(const float4*)(g2 + base + 4);
    float4 bc = *(const float4*)(b2 + base), bd = *(const float4*)(b2 + base + 4);
    float g2v[8] = {gc.x, gc.y, gc.z, gc.w, gd.x, gd.y, gd.z, gd.w};
    float b2v[8] = {bc.x, bc.y, bc.z, bc.w, bd.x, bd.y, bd.z, bd.w};
    float r[8];
    #pragma unroll
    for (int jj = 0; jj < 8; jj++) r[jj] = (tvec[jj] - m2) * inv2 * g2v[jj] + b2v[jj];
    float* pf = yf + row * 512 + base;
    *(float4*)pf = (float4){r[0], r[1], r[2], r[3]};
    *(float4*)(pf + 4) = (float4){r[4], r[5], r[6], r[7]};
    bf16x8 ov;
    #pragma unroll
    for (int jj = 0; jj < 8; jj++) ov[jj] = (short)f2bf(r[jj]);
    *(bf16x8*)(yb + row * 512 + base) = ov;
}

// =================== lnff ===================
__global__ __launch_bounds__(256)
void lnff_k(const float* __restrict__ y1, const float* __restrict__ parts,
            const float* __restrict__ bias,
            const float* __restrict__ g, const float* __restrict__ be,
            float* __restrict__ o, unsigned short* __restrict__ ob)
{
    const int wv = threadIdx.x >> 6, lane = threadIdx.x & 63;
    const long row = (long)blockIdx.x * 4 + wv;
    const int base = lane * 8;
    const float* pa = y1 + row * 512 + base;
    float v[8];
    {
        float4 x0 = *(const float4*)pa, x1 = *(const float4*)(pa + 4);
        float4 w0 = *(const float4*)(bias + base), w1 = *(const float4*)(bias + base + 4);
        v[0] = x0.x + w0.x; v[1] = x0.y + w0.y; v[2] = x0.z + w0.z; v[3] = x0.w + w0.w;
        v[4] = x1.x + w1.x; v[5] = x1.y + w1.y; v[6] = x1.z + w1.z; v[7] = x1.w + w1.w;
    }
    #pragma unroll
    for (int k = 0; k < 4; k++) {
        const float* pp = parts + (long)k * 1048576 + row * 512 + base;
        float4 a0 = *(const float4*)pp, a1 = *(const float4*)(pp + 4);
        v[0] += a0.x; v[1] += a0.y; v[2] += a0.z; v[3] += a0.w;
        v[4] += a1.x; v[5] += a1.y; v[6] += a1.z; v[7] += a1.w;
    }
    float s = 0.f;
    #pragma unroll
    for (int jj = 0; jj < 8; jj++) s += v[jj];
    #pragma unroll
    for (int off = 32; off; off >>= 1) s += __shfl_xor(s, off);
    float mean = s * (1.f / 512.f);
    float vs = 0.f;
    #pragma unroll
    for (int jj = 0; jj < 8; jj++) { float d = v[jj] - mean; vs += d * d; }
    #pragma unroll
    for (int off = 32; off; off >>= 1) vs += __shfl_xor(vs, off);
    float inv = rsqrtf(vs * (1.f / 512.f) + 1e-5f);
    float4 g0 = *(const float4*)(g + base), g1 = *(const float4*)(g + base + 4);
    float4 e0 = *(const float4*)(be + base), e1 = *(const float4*)(be + base + 4);
    float gg[8] = {g0.x, g0.y, g0.z, g0.w, g1.x, g1.y, g1.z, g1.w};
    float ee[8] = {e0.x, e0.y, e0.z, e0.w, e1.x, e1.y, e1.z, e1.w};
    float r[8];
    #pragma unroll
    for (int jj = 0; jj < 8; jj++) r[jj] = (v[jj] - mean) * inv * gg[jj] + ee[jj];
    float* po = o + row * 512 + base;
    *(float4*)po = (float4){r[0], r[1], r[2], r[3]};
    *(float4*)(po + 4) = (float4){r[4], r[5], r[6], r[7]};
    bf16x8 ov;
    #pragma unroll
    for (int jj = 0; jj < 8; jj++) ov[jj] = (short)f2bf(r[jj]);
    *(bf16x8*)(ob + row * 512 + base) = ov;
}

// =================== seasonal softmax ===================
__global__ void softmax5_k(const float* __restrict__ comb, float* __restrict__ c5)
{
    if (threadIdx.x == 0 && blockIdx.x == 0) {
        float c[5]; float m = -1e30f;
        for (int k = 0; k < 5; k++) { c[k] = comb[k]; m = fmaxf(m, c[k]); }
        float s = 0.f;
        for (int k = 0; k < 5; k++) { c[k] = __expf(c[k] - m); s += c[k]; }
        for (int k = 0; k < 5; k++) c5[k] = c[k] / s;
    }
}

// ============================ host ============================
#define G3(BM,BN,OBF,BIAS,GACT,SPART,DUAL,VTR, A,B,C,C2,bias_, M,N,NKT,SKN, lda,ldb,ldc, alpha, mA,a1,a2, mB,b1,b2, mC,c1,c2, bstr, pstr, Zg) \
    gemm3<BM,BN,OBF,BIAS,GACT,SPART,DUAL,VTR><<<dim3((M)/(BM), ((N)+(BN)-1)/(BN), (Zg)), dim3(256), 0, stream>>>( \
        (A),(B),(C),(C2),(bias_),(M),(N),(NKT),(SKN),(lda),(ldb),(ldc),(alpha), \
        (mA),(long)(a1),(long)(a2),(mB),(long)(b1),(long)(b2),(mC),(long)(c1),(long)(c2),(bstr),(long)(pstr))

extern "C" void kernel_launch(void* const* d_in, const int* in_sizes, int n_in,
                              void* d_out, int out_size, void* d_ws, size_t ws_size,
                              hipStream_t stream)
{
    (void)in_sizes; (void)n_in; (void)out_size; (void)ws_size;
    const float* x    = (const float*)d_in[0];
    const float* t1w  = (const float*)d_in[1];
    const float* t1b  = (const float*)d_in[2];
    const float* t2w  = (const float*)d_in[3];
    const float* t2b  = (const float*)d_in[4];
    const float* s1w  = (const float*)d_in[5];
    const float* s1b  = (const float*)d_in[6];
    const float* s2w  = (const float*)d_in[7];
    const float* s2b  = (const float*)d_in[8];
    const float* r1w  = (const float*)d_in[9];
    const float* r1b  = (const float*)d_in[10];
    const float* r2w  = (const float*)d_in[11];
    const float* r2b  = (const float*)d_in[12];
    const float* comb = (const float*)d_in[13];
    const float* wq   = (const float*)d_in[14];
    const float* wk   = (const float*)d_in[15];
    const float* wvv  = (const float*)d_in[16];
    const float* wow  = (const float*)d_in[17];
    const float* wob  = (const float*)d_in[18];
    const float* relk = (const float*)d_in[19];
    const float* relv = (const float*)d_in[20];
    const float* lag  = (const float*)d_in[21];
    const float* labi = (const float*)d_in[22];
    const float* f1w  = (const float*)d_in[23];
    const float* f1b  = (const float*)d_in[24];
    const float* f2w  = (const float*)d_in[25];
    const float* f2b  = (const float*)d_in[26];
    const float* n1g  = (const float*)d_in[27];
    const float* n1b  = (const float*)d_in[28];
    const float* n2g  = (const float*)d_in[29];
    const float* n2b  = (const float*)d_in[30];

    char* ws = (char*)d_ws;
    #define OFFK(kb) (ws + (size_t)(kb) * 1024)
    float* X    = (float*)OFFK(0);          // 4MB [2048][512]
    float* T3   = (float*)OFFK(8192);       // 4MB
    float* PART = (float*)OFFK(12288);      // 16MB [4][2048][512]
    float* OP   = PART;                     // attn partials alias (8MB)
    float* ML   = PART + 2097152;           // attn (m,l) alias (256KB)
    unsigned short* Xb   = (unsigned short*)OFFK(45056);  // 2MB
    unsigned short* Xb0  = (unsigned short*)OFFK(47104);  // 2MB
    unsigned short* QKVb = (unsigned short*)OFFK(49152);  // 6MB [2048][1536] (aliases Hb)
    unsigned short* VT   = (unsigned short*)OFFK(55296);  // 2MB [32][64][512]
    unsigned short* CTXb = (unsigned short*)OFFK(57344);  // 2MB
    unsigned short* T3b  = (unsigned short*)OFFK(59392);  // 2MB
    unsigned short* FFb  = (unsigned short*)OFFK(61440);  // 8MB [2048][2048]
    unsigned short* W1   = (unsigned short*)OFFK(69632);  // 1.5MB
    unsigned short* W2   = (unsigned short*)OFFK(71168);  // 1.5MB
    float* b1c = (float*)OFFK(72704);
    float* bc  = (float*)OFFK(72712);
    float* c5  = (float*)OFFK(72716);
    unsigned short* qkvT = (unsigned short*)OFFK(119808); // 9MB
    unsigned short* woT  = (unsigned short*)OFFK(129024); // 3MB
    unsigned short* f1wT = (unsigned short*)OFFK(132096); // 12MB
    unsigned short* f2wT = (unsigned short*)OFFK(144384); // 12MB
    unsigned short* relkb= (unsigned short*)OFFK(156672); // [6][1088][64]
    unsigned short* rvT  = (unsigned short*)OFFK(157488); // [6][64][1056]
    unsigned short* Hb   = QKVb;

    // ---------------- prep ----------------
    castpad_k<<<dim3(1024, 1, 1), 256, 0, stream>>>(x, Xb0, 2048, 512, 1048576, 1048576, 1048576);
    softmax5_k<<<dim3(1), 64, 0, stream>>>(comb, c5);
    wprep_k<<<dim3(16, 16, 11), 256, 0, stream>>>(t1w, r1w, s1w, t2w, r2w, s2w, c5, W1, W2,
                                                  t1b, r1b, s1b, t2b, r2b, s2b, b1c, bc);
    qkvwo_tr<<<dim3(16, 16, 24), 256, 0, stream>>>(wq, wk, wvv, wow, qkvT, woT);
    trcast_k<<<dim3(64, 16, 6), 256, 0, stream>>>(f1w, f1wT, 512, 2048, 512, 1048576, 1048576, nullptr, 0);
    trcast_k<<<dim3(16, 64, 6), 256, 0, stream>>>(f2w, f2wT, 2048, 512, 2048, 1048576, 1048576, nullptr, 0);
    trcast_k<<<dim3(2, 33, 6), 256, 0, stream>>>(relv, rvT, 1025, 64, 1056, 65600, 67584, nullptr, 0);
    castpad_k<<<dim3(272, 1, 6), 256, 0, stream>>>(relk, relkb, 1025, 64, 65600, 69632, 69632);

    // ---------------- seasonal decomposition ----------------
    G3(64,64,true,true,true,false,false,false,  Xb0, W1, Hb, nullptr, b1c, 2048,1536,8,1, 512,512,1536, 1.f,
       1,0,0, 1,0,0, 1,0,0, 0,0, 1);
    // stage 2: split-K 3 (768 blocks) + reduce
    G3(64,64,false,false,false,true,false,false, Hb, W2, PART, nullptr, nullptr, 2048,512,8,3, 1536,1536,512, 1.f,
       1,0,0, 1,0,0, 1,0,0, 0,1048576, 3);
    red3xb_k<<<dim3(1024), 256, 0, stream>>>(PART, bc, X, Xb);

    // ---------------- transformer layers ----------------
    for (int l = 0; l < NL; ++l) {
        const unsigned short* qkvTl = qkvT + (long)l * 786432;
        const unsigned short* woTl  = woT + (long)l * 262144;
        const unsigned short* f1Tl  = f1wT + (long)l * 1048576;
        const unsigned short* f2Tl  = f2wT + (long)l * 1048576;
        const unsigned short* rkl   = relkb + (long)l * 69632;
        const unsigned short* rvl   = rvT + (long)l * 67584;

        // QKV (merged, 64x64, 768 blocks; V tiles written transposed to VT)
        G3(64,64,true,false,false,false,false,true, Xb, qkvTl, QKVb, VT, nullptr, 2048,1536,8,1, 512,512,1536, 1.f,
           1,0,0, 1,0,0, 1,0,0, 0,0, 1);
        // split-KV flash attention (512 blocks, 2/CU) + merge
        fused_attn4<<<dim3(8, 32, 2), 256, 0, stream>>>(QKVb, VT, rkl, rvl, OP, ML);
        attn_merge<<<dim3(4096), 256, 0, stream>>>(OP, ML, CTXb);
        // out = ctx @ wo (64x64, split-K 2 -> 512 blocks)
        G3(64,64,false,false,false,true,false,false, CTXb, woTl, PART, nullptr, nullptr, 2048,512,4,2, 512,512,512, 1.f,
           1,0,0, 1,0,0, 1,0,0, 0,1048576, 2);
        // y1 = LN(x + LN(wo_out + wob + x))
        ln2x_k<<<dim3(512), 256, 0, stream>>>(PART, PART + 1048576, wob + l * 512, X,
                                              lag + l * 512, labi + l * 512,
                                              n1g + l * 512, n1b + l * 512, T3, T3b);
        // FF1 (64x64, 1024 blocks)
        G3(64,64,true,true,true,false,false,false, T3b, f1Tl, FFb, nullptr, f1b + l * 2048, 2048,2048,8,1, 512,512,2048, 1.f,
           1,0,0, 1,0,0, 1,0,0, 0,0, 1);
        // FF2 (64x64, split-K 4 -> 1024 blocks)
        G3(64,64,false,false,false,true,false,false, FFb, f2Tl, PART, nullptr, nullptr, 2048,512,8,4, 2048,2048,512, 1.f,
           1,0,0, 1,0,0, 1,0,0, 0,1048576, 4);
        // y = LN(y1 + ff)
        float* outp = (l == NL - 1) ? (float*)d_out : X;
        lnff_k<<<dim3(512), 256, 0, stream>>>(T3, PART, f2b + l * 512,
                                              n2g + l * 512, n2b + l * 512, outp, Xb);
    }
}